// Round 5
// baseline (560.925 us; speedup 1.0000x reference)
//
#include <hip/hip_runtime.h>

// ---------------------------------------------------------------------------
// SelfAttention (GQA + nonstandard RoPE), S=2048, HIDDEN=2048, 32 q-heads,
// 8 kv-heads, D=64.  Inputs/outputs FLOAT32; internal bf16 MFMA, fp32 accum.
// R5: flash attention with transposed scores (S^T = K.Q^T): S^T's C-layout
// IS the A-frag layout of the K=16 MFMA, so P never leaves registers —
// no LDS, no barriers, no asm clobbers in the K-loop.
// ---------------------------------------------------------------------------

typedef __bf16 bf16_t;
typedef __bf16 bf16x4 __attribute__((ext_vector_type(4)));
typedef __bf16 bf16x8 __attribute__((ext_vector_type(8)));
typedef float  f32x4  __attribute__((ext_vector_type(4)));
typedef short  s16x4  __attribute__((ext_vector_type(4)));

#define S_LEN   2048
#define HID     2048
#define NKV     8
#define NH      32
#define DHEAD   64
#define KVW     (NKV * DHEAD)   // 512

// ---- module-global scratch (rewritten fully each call) ---------------------
__device__ __align__(16) bf16_t g_xb[S_LEN * HID];      // x converted to bf16
__device__ __align__(16) bf16_t g_wT[HID * HID];        // transposed bf16 weight (reused 4x)
__device__ __align__(16) bf16_t g_q [S_LEN * HID];      // roped Q activations
__device__ __align__(16) bf16_t g_k [S_LEN * KVW];      // roped K activations
__device__ __align__(16) bf16_t g_vT[KVW * S_LEN];      // V^T  [d_total][S]
__device__ __align__(16) bf16_t g_om[S_LEN * HID];      // attention output (pre o_proj)
__device__ float g_ropeC[S_LEN * 32];
__device__ float g_ropeS[S_LEN * 32];

static __device__ inline s16x4 bc4(bf16x4 v) { s16x4 r; __builtin_memcpy(&r, &v, 8); return r; }

// ---------------------------------------------------------------------------
// RoPE table: f64-exact angle, f64 sin/cos, stored f32.
// inv_freq dtype sniff: word0==0x3F800000 <=> f32.
// ---------------------------------------------------------------------------
__global__ void rope_table_kernel(const void* __restrict__ invf_raw) {
    int t = blockIdx.x * blockDim.x + threadIdx.x;   // 0 .. 65535
    int s = t >> 5, j = t & 31;
    float f;
    if (*(const unsigned*)invf_raw == 0x3F800000u) {
        f = ((const float*)invf_raw)[j];
    } else {
        unsigned u = ((unsigned)((const unsigned short*)invf_raw)[j]) << 16;
        __builtin_memcpy(&f, &u, 4);
    }
    double a = (double)s * (double)f;
    g_ropeC[t] = (float)cos(a);
    g_ropeS[t] = (float)sin(a);
}

// ---------------------------------------------------------------------------
// x f32 -> bf16 (vectorized 4/thread).
// ---------------------------------------------------------------------------
__global__ __launch_bounds__(256)
void convert_x_kernel(const float* __restrict__ x) {
    int t = blockIdx.x * 256 + threadIdx.x;          // 0 .. 1M-1
    float4 v = reinterpret_cast<const float4*>(x)[t];
    bf16x4 o;
    o[0] = (bf16_t)v.x; o[1] = (bf16_t)v.y; o[2] = (bf16_t)v.z; o[3] = (bf16_t)v.w;
    *reinterpret_cast<bf16x4*>(&g_xb[(size_t)t * 4]) = o;
}

// ---------------------------------------------------------------------------
// f32 weight [R][C] -> transposed bf16 g_wT [C][R].  Tile 64x64, block (64,4).
// ---------------------------------------------------------------------------
__global__ __launch_bounds__(256)
void transpose_kernel(const float* __restrict__ in, int R, int C) {
    __shared__ bf16_t tile[64][65];
    int c0 = blockIdx.x * 64, r0 = blockIdx.y * 64;
    int tx = threadIdx.x, ty = threadIdx.y;
    #pragma unroll
    for (int r = ty; r < 64; r += 4)
        tile[r][tx] = (bf16_t)in[(size_t)(r0 + r) * C + c0 + tx];
    __syncthreads();
    #pragma unroll
    for (int r = ty; r < 64; r += 4)
        g_wT[(size_t)(c0 + r) * R + r0 + tx] = tile[tx][r];
}

// ---------------------------------------------------------------------------
// MFMA GEMM: C[M,N] = A[M,K] * B[K,N], B transposed in g_wT [N][K] (bf16).
// 128x128 tile, 4 waves 2x2, each wave 64x64 = 4x4 mfma tiles, BK=32.
// asel: 0 = g_xb, 1 = g_om.
// mode 0: f32 store to Cf.   mode 1: RoPE epilogue -> bf16 (csel 1=g_q,
// 2=g_k).  mode 2: transposed bf16 store -> g_vT.
// ---------------------------------------------------------------------------
__global__ __launch_bounds__(256)
void gemm_bt_kernel(float* __restrict__ Cf, int asel, int csel,
                    int M, int N, int K, int mode) {
    __shared__ __align__(16) bf16_t As[128][40];
    __shared__ __align__(16) bf16_t Bs[128][40];

    const bf16_t* A = (asel == 0) ? g_xb : g_om;
    bf16_t* Cb = (csel == 1) ? g_q : (csel == 2 ? g_k : g_vT);

    int t    = threadIdx.x;
    int lane = t & 63, wid = t >> 6;
    int quad = lane >> 4, l15 = lane & 15;
    int m0 = blockIdx.y * 128, n0 = blockIdx.x * 128;
    int wm = (wid >> 1) * 64, wn = (wid & 1) * 64;

    f32x4 acc[4][4];
    #pragma unroll
    for (int im = 0; im < 4; ++im)
        #pragma unroll
        for (int in = 0; in < 4; ++in)
            #pragma unroll
            for (int r = 0; r < 4; ++r) acc[im][in][r] = 0.f;

    for (int kt = 0; kt < K; kt += 32) {
        __syncthreads();
        #pragma unroll
        for (int i = t; i < 512; i += 256) {
            int row = i >> 2, seg = i & 3;
            const int4* pa = reinterpret_cast<const int4*>(A + (size_t)(m0 + row) * K + kt + seg * 8);
            *reinterpret_cast<int4*>(&As[row][seg * 8]) = *pa;
            const int4* pb = reinterpret_cast<const int4*>(g_wT + (size_t)(n0 + row) * K + kt + seg * 8);
            *reinterpret_cast<int4*>(&Bs[row][seg * 8]) = *pb;
        }
        __syncthreads();

        bf16x8 af[4], bfr[4];
        #pragma unroll
        for (int im = 0; im < 4; ++im)
            af[im] = *reinterpret_cast<const bf16x8*>(&As[wm + im * 16 + l15][quad * 8]);
        #pragma unroll
        for (int in = 0; in < 4; ++in)
            bfr[in] = *reinterpret_cast<const bf16x8*>(&Bs[wn + in * 16 + l15][quad * 8]);
        #pragma unroll
        for (int im = 0; im < 4; ++im)
            #pragma unroll
            for (int in = 0; in < 4; ++in)
                acc[im][in] = __builtin_amdgcn_mfma_f32_16x16x32_bf16(af[im], bfr[in], acc[im][in], 0, 0, 0);
    }

    if (mode == 0) {
        #pragma unroll
        for (int im = 0; im < 4; ++im) {
            int rowb = m0 + wm + im * 16 + quad * 4;
            #pragma unroll
            for (int in = 0; in < 4; ++in) {
                int col = n0 + wn + in * 16 + l15;
                #pragma unroll
                for (int r = 0; r < 4; ++r)
                    Cf[(size_t)(rowb + r) * N + col] = acc[im][in][r];
            }
        }
    } else if (mode == 1) {
        // out[d] = x[d]*cos + x[d+32]*sin ; out[d+32] = x[d]*sin - x[d+32]*cos
        int colbase = n0 + wn;   // 64-aligned == head base
        #pragma unroll
        for (int im = 0; im < 4; ++im) {
            #pragma unroll
            for (int r = 0; r < 4; ++r) {
                int row = m0 + wm + im * 16 + quad * 4 + r;
                #pragma unroll
                for (int in = 0; in < 2; ++in) {
                    int d = in * 16 + l15;                 // 0..31
                    float a  = acc[im][in][r];
                    float b  = acc[im][in + 2][r];
                    float cc = g_ropeC[row * 32 + d];
                    float ss = g_ropeS[row * 32 + d];
                    Cb[(size_t)row * N + colbase + d]      = (bf16_t)(a * cc + b * ss);
                    Cb[(size_t)row * N + colbase + 32 + d] = (bf16_t)(a * ss - b * cc);
                }
            }
        }
    } else { // mode 2: transposed store (g_vT [d_total][S])
        #pragma unroll
        for (int im = 0; im < 4; ++im) {
            int rowb = m0 + wm + im * 16 + quad * 4;
            #pragma unroll
            for (int in = 0; in < 4; ++in) {
                int col = n0 + wn + in * 16 + l15;
                #pragma unroll
                for (int r = 0; r < 4; ++r)
                    Cb[(size_t)col * M + (rowb + r)] = (bf16_t)acc[im][in][r];
            }
        }
    }
}

// ---------------------------------------------------------------------------
// Flash attention (causal, GQA), register-only P.
// One wave = 16 query rows of one q-head.  Per 16-key subtile:
//   S^T = K.Q^T via two 16x16x32 MFMAs (A = K-frag, B = Q-frag).
//   S^T C-layout (row=quad*4+r = k-idx, col=l15 = q) == A-frag layout of
//   v_mfma_f32_16x16x16bf16_1k (A[m=l15][k=quad*4+j]), so after mask+exp the
//   P fragment feeds PV and the all-ones row-sum MFMA directly from VGPRs.
// Fixed-shift softmax p = exp(s-16) (scores bounded; shift cancels in O/l).
// No LDS, no barriers — loads hoist freely across iterations.
// High-qb (long) waves launch first to pack the tail.
// ---------------------------------------------------------------------------
__global__ __launch_bounds__(256)
void flash_kernel() {
    int t    = threadIdx.x;
    int lane = t & 63, wid = t >> 6;
    int quad = lane >> 4, l15 = lane & 15;
    int gw   = blockIdx.x * 4 + wid;
    int head = gw & 31;
    int qb   = 127 - (gw >> 5);      // reversed: longest waves first
    int hk   = head >> 2;

    bf16x8 aq[2];
    {
        const bf16_t* qp = g_q + (size_t)(qb * 16 + l15) * HID + head * 64 + quad * 8;
        aq[0] = *reinterpret_cast<const bf16x8*>(qp);
        aq[1] = *reinterpret_cast<const bf16x8*>(qp + 32);
        #pragma unroll
        for (int j = 0; j < 8; ++j) {   // fold 1/sqrt(64) into Q (exact: exponent-only)
            aq[0][j] = (bf16_t)((float)aq[0][j] * 0.125f);
            aq[1][j] = (bf16_t)((float)aq[1][j] * 0.125f);
        }
    }

    bf16x4 ones4;
    #pragma unroll
    for (int j = 0; j < 4; ++j) ones4[j] = (bf16_t)1.0f;
    s16x4 ones_s = bc4(ones4);

    f32x4 oacc[4], liacc;
    #pragma unroll
    for (int dt = 0; dt < 4; ++dt)
        #pragma unroll
        for (int r = 0; r < 4; ++r) oacc[dt][r] = 0.f;
    #pragma unroll
    for (int r = 0; r < 4; ++r) liacc[r] = 0.f;

    int qcol = qb * 16 + l15;        // the query row this lane's S^T column is
    int nkt  = (qb + 2) >> 1;        // 32-key iterations (2 x 16-key subtiles)
    for (int kt = 0; kt < nkt; ++kt) {
        #pragma unroll
        for (int sub = 0; sub < 2; ++sub) {
            int kb = kt * 32 + sub * 16;
            const bf16_t* kp = g_k + (size_t)(kb + l15) * KVW + hk * 64 + quad * 8;
            bf16x8 kf0 = *reinterpret_cast<const bf16x8*>(kp);
            bf16x8 kf1 = *reinterpret_cast<const bf16x8*>(kp + 32);

            f32x4 sacc;
            #pragma unroll
            for (int r = 0; r < 4; ++r) sacc[r] = 0.f;
            sacc = __builtin_amdgcn_mfma_f32_16x16x32_bf16(kf0, aq[0], sacc, 0, 0, 0);
            sacc = __builtin_amdgcn_mfma_f32_16x16x32_bf16(kf1, aq[1], sacc, 0, 0, 0);

            // mask + exp -> P fragment (A-layout for K=16 MFMA), in registers
            bf16x4 pa;
            #pragma unroll
            for (int r = 0; r < 4; ++r) {
                int kk = kb + quad * 4 + r;
                pa[r] = (bf16_t)((kk <= qcol) ? __expf(sacc[r] - 16.0f) : 0.0f);
            }
            s16x4 pas = bc4(pa);

            liacc = __builtin_amdgcn_mfma_f32_16x16x16bf16_1k(pas, ones_s, liacc, 0, 0, 0);
            #pragma unroll
            for (int dt = 0; dt < 4; ++dt) {
                const bf16_t* vp = g_vT + (size_t)(hk * 64 + dt * 16 + l15) * S_LEN + kb + quad * 4;
                bf16x4 bv = *reinterpret_cast<const bf16x4*>(vp);
                oacc[dt] = __builtin_amdgcn_mfma_f32_16x16x16bf16_1k(pas, bc4(bv), oacc[dt], 0, 0, 0);
            }
        }
    }

    // O/D layout: row(q) = quad*4+r, col(d) = dt*16+l15 ; liacc[r] = l(q).
    #pragma unroll
    for (int r = 0; r < 4; ++r) {
        float inv = 1.0f / liacc[r];
        int row = qb * 16 + quad * 4 + r;
        #pragma unroll
        for (int dt = 0; dt < 4; ++dt)
            g_om[(size_t)row * HID + head * 64 + dt * 16 + l15] = (bf16_t)(oacc[dt][r] * inv);
    }
}

// ---------------------------------------------------------------------------
// Launch
// ---------------------------------------------------------------------------
extern "C" void kernel_launch(void* const* d_in, const int* in_sizes, int n_in,
                              void* d_out, int out_size, void* d_ws, size_t ws_size,
                              hipStream_t stream) {
    const float* x    = (const float*)d_in[0];
    const float* qpW  = (const float*)d_in[1];
    const float* kpW  = (const float*)d_in[2];
    const float* vpW  = (const float*)d_in[3];
    const float* opW  = (const float*)d_in[4];
    const void*  invf = d_in[5];
    float* out = (float*)d_out;

    dim3 tb(64, 4);

    rope_table_kernel<<<256, 256, 0, stream>>>(invf);
    convert_x_kernel<<<4096, 256, 0, stream>>>(x);

    // Q = rope(x @ q_proj)
    transpose_kernel<<<dim3(32, 32), tb, 0, stream>>>(qpW, HID, HID);
    gemm_bt_kernel<<<dim3(16, 16), 256, 0, stream>>>(nullptr, 0, 1, S_LEN, HID, HID, 1);
    // K = rope(x @ k_proj)
    transpose_kernel<<<dim3(8, 32), tb, 0, stream>>>(kpW, HID, KVW);
    gemm_bt_kernel<<<dim3(4, 16), 256, 0, stream>>>(nullptr, 0, 2, S_LEN, KVW, HID, 1);
    // vT = (x @ v_proj)^T
    transpose_kernel<<<dim3(8, 32), tb, 0, stream>>>(vpW, HID, KVW);
    gemm_bt_kernel<<<dim3(4, 16), 256, 0, stream>>>(nullptr, 0, 3, S_LEN, KVW, HID, 2);
    // attention
    flash_kernel<<<1024, 256, 0, stream>>>();
    // out = g_om @ o_proj  (f32 store)
    transpose_kernel<<<dim3(32, 32), tb, 0, stream>>>(opW, HID, HID);
    gemm_bt_kernel<<<dim3(16, 16), 256, 0, stream>>>(out, 1, 0, S_LEN, HID, HID, 0);
}

// Round 6
// 408.801 us; speedup vs baseline: 1.3721x; 1.3721x over previous
//
#include <hip/hip_runtime.h>

// ---------------------------------------------------------------------------
// SelfAttention (GQA + nonstandard RoPE), S=2048, HIDDEN=2048, 32 q-heads,
// 8 kv-heads, D=64.  Inputs/outputs FLOAT32; internal bf16 MFMA, fp32 accum.
// R6: flash rebuilt block-cooperative: block = 4 waves = 4 q-heads of one
// kv-group, 32 queries/wave; 64-key K/V tiles staged in LDS (m97 2-barrier
// pattern); P stays in registers via the transposed-score trick (R5-verified).
// ---------------------------------------------------------------------------

typedef __bf16 bf16_t;
typedef __bf16 bf16x4 __attribute__((ext_vector_type(4)));
typedef __bf16 bf16x8 __attribute__((ext_vector_type(8)));
typedef float  f32x4  __attribute__((ext_vector_type(4)));
typedef short  s16x4  __attribute__((ext_vector_type(4)));

#define S_LEN   2048
#define HID     2048
#define NKV     8
#define NH      32
#define DHEAD   64
#define KVW     (NKV * DHEAD)   // 512

// ---- module-global scratch (rewritten fully each call) ---------------------
__device__ __align__(16) bf16_t g_xb[S_LEN * HID];      // x converted to bf16
__device__ __align__(16) bf16_t g_wT[HID * HID];        // transposed bf16 weight (reused 4x)
__device__ __align__(16) bf16_t g_q [S_LEN * HID];      // roped Q activations
__device__ __align__(16) bf16_t g_k [S_LEN * KVW];      // roped K activations
__device__ __align__(16) bf16_t g_vT[KVW * S_LEN];      // V^T  [d_total][S]
__device__ __align__(16) bf16_t g_om[S_LEN * HID];      // attention output (pre o_proj)
__device__ float g_ropeC[S_LEN * 32];
__device__ float g_ropeS[S_LEN * 32];

static __device__ inline s16x4 bc4(bf16x4 v) { s16x4 r; __builtin_memcpy(&r, &v, 8); return r; }

// ---------------------------------------------------------------------------
// RoPE table: f64-exact angle, f64 sin/cos, stored f32.
// inv_freq dtype sniff: word0==0x3F800000 <=> f32.
// ---------------------------------------------------------------------------
__global__ void rope_table_kernel(const void* __restrict__ invf_raw) {
    int t = blockIdx.x * blockDim.x + threadIdx.x;   // 0 .. 65535
    int s = t >> 5, j = t & 31;
    float f;
    if (*(const unsigned*)invf_raw == 0x3F800000u) {
        f = ((const float*)invf_raw)[j];
    } else {
        unsigned u = ((unsigned)((const unsigned short*)invf_raw)[j]) << 16;
        __builtin_memcpy(&f, &u, 4);
    }
    double a = (double)s * (double)f;
    g_ropeC[t] = (float)cos(a);
    g_ropeS[t] = (float)sin(a);
}

// ---------------------------------------------------------------------------
// x f32 -> bf16 (vectorized 4/thread).
// ---------------------------------------------------------------------------
__global__ __launch_bounds__(256)
void convert_x_kernel(const float* __restrict__ x) {
    int t = blockIdx.x * 256 + threadIdx.x;          // 0 .. 1M-1
    float4 v = reinterpret_cast<const float4*>(x)[t];
    bf16x4 o;
    o[0] = (bf16_t)v.x; o[1] = (bf16_t)v.y; o[2] = (bf16_t)v.z; o[3] = (bf16_t)v.w;
    *reinterpret_cast<bf16x4*>(&g_xb[(size_t)t * 4]) = o;
}

// ---------------------------------------------------------------------------
// f32 weight [R][C] -> transposed bf16 g_wT [C][R].  Tile 64x64, block (64,4).
// ---------------------------------------------------------------------------
__global__ __launch_bounds__(256)
void transpose_kernel(const float* __restrict__ in, int R, int C) {
    __shared__ bf16_t tile[64][65];
    int c0 = blockIdx.x * 64, r0 = blockIdx.y * 64;
    int tx = threadIdx.x, ty = threadIdx.y;
    #pragma unroll
    for (int r = ty; r < 64; r += 4)
        tile[r][tx] = (bf16_t)in[(size_t)(r0 + r) * C + c0 + tx];
    __syncthreads();
    #pragma unroll
    for (int r = ty; r < 64; r += 4)
        g_wT[(size_t)(c0 + r) * R + r0 + tx] = tile[tx][r];
}

// ---------------------------------------------------------------------------
// MFMA GEMM: C[M,N] = A[M,K] * B[K,N], B transposed in g_wT [N][K] (bf16).
// 128x128 tile, 4 waves 2x2, each wave 64x64 = 4x4 mfma tiles, BK=32.
// asel: 0 = g_xb, 1 = g_om.
// mode 0: f32 store to Cf.   mode 1: RoPE epilogue -> bf16 (csel 1=g_q,
// 2=g_k).  mode 2: transposed bf16 store -> g_vT.
// ---------------------------------------------------------------------------
__global__ __launch_bounds__(256)
void gemm_bt_kernel(float* __restrict__ Cf, int asel, int csel,
                    int M, int N, int K, int mode) {
    __shared__ __align__(16) bf16_t As[128][40];
    __shared__ __align__(16) bf16_t Bs[128][40];

    const bf16_t* A = (asel == 0) ? g_xb : g_om;
    bf16_t* Cb = (csel == 1) ? g_q : (csel == 2 ? g_k : g_vT);

    int t    = threadIdx.x;
    int lane = t & 63, wid = t >> 6;
    int quad = lane >> 4, l15 = lane & 15;
    int m0 = blockIdx.y * 128, n0 = blockIdx.x * 128;
    int wm = (wid >> 1) * 64, wn = (wid & 1) * 64;

    f32x4 acc[4][4];
    #pragma unroll
    for (int im = 0; im < 4; ++im)
        #pragma unroll
        for (int in = 0; in < 4; ++in)
            #pragma unroll
            for (int r = 0; r < 4; ++r) acc[im][in][r] = 0.f;

    for (int kt = 0; kt < K; kt += 32) {
        __syncthreads();
        #pragma unroll
        for (int i = t; i < 512; i += 256) {
            int row = i >> 2, seg = i & 3;
            const int4* pa = reinterpret_cast<const int4*>(A + (size_t)(m0 + row) * K + kt + seg * 8);
            *reinterpret_cast<int4*>(&As[row][seg * 8]) = *pa;
            const int4* pb = reinterpret_cast<const int4*>(g_wT + (size_t)(n0 + row) * K + kt + seg * 8);
            *reinterpret_cast<int4*>(&Bs[row][seg * 8]) = *pb;
        }
        __syncthreads();

        bf16x8 af[4], bfr[4];
        #pragma unroll
        for (int im = 0; im < 4; ++im)
            af[im] = *reinterpret_cast<const bf16x8*>(&As[wm + im * 16 + l15][quad * 8]);
        #pragma unroll
        for (int in = 0; in < 4; ++in)
            bfr[in] = *reinterpret_cast<const bf16x8*>(&Bs[wn + in * 16 + l15][quad * 8]);
        #pragma unroll
        for (int im = 0; im < 4; ++im)
            #pragma unroll
            for (int in = 0; in < 4; ++in)
                acc[im][in] = __builtin_amdgcn_mfma_f32_16x16x32_bf16(af[im], bfr[in], acc[im][in], 0, 0, 0);
    }

    if (mode == 0) {
        #pragma unroll
        for (int im = 0; im < 4; ++im) {
            int rowb = m0 + wm + im * 16 + quad * 4;
            #pragma unroll
            for (int in = 0; in < 4; ++in) {
                int col = n0 + wn + in * 16 + l15;
                #pragma unroll
                for (int r = 0; r < 4; ++r)
                    Cf[(size_t)(rowb + r) * N + col] = acc[im][in][r];
            }
        }
    } else if (mode == 1) {
        // out[d] = x[d]*cos + x[d+32]*sin ; out[d+32] = x[d]*sin - x[d+32]*cos
        int colbase = n0 + wn;   // 64-aligned == head base
        #pragma unroll
        for (int im = 0; im < 4; ++im) {
            #pragma unroll
            for (int r = 0; r < 4; ++r) {
                int row = m0 + wm + im * 16 + quad * 4 + r;
                #pragma unroll
                for (int in = 0; in < 2; ++in) {
                    int d = in * 16 + l15;                 // 0..31
                    float a  = acc[im][in][r];
                    float b  = acc[im][in + 2][r];
                    float cc = g_ropeC[row * 32 + d];
                    float ss = g_ropeS[row * 32 + d];
                    Cb[(size_t)row * N + colbase + d]      = (bf16_t)(a * cc + b * ss);
                    Cb[(size_t)row * N + colbase + 32 + d] = (bf16_t)(a * ss - b * cc);
                }
            }
        }
    } else { // mode 2: transposed store (g_vT [d_total][S])
        #pragma unroll
        for (int im = 0; im < 4; ++im) {
            int rowb = m0 + wm + im * 16 + quad * 4;
            #pragma unroll
            for (int in = 0; in < 4; ++in) {
                int col = n0 + wn + in * 16 + l15;
                #pragma unroll
                for (int r = 0; r < 4; ++r)
                    Cb[(size_t)col * M + (rowb + r)] = (bf16_t)acc[im][in][r];
            }
        }
    }
}

// ---------------------------------------------------------------------------
// Flash attention (causal, GQA), block-cooperative, register-only P.
// Block = 4 waves = the 4 q-heads of kv-group hk; each wave owns 32 queries
// (2 M-tiles of 16).  K-loop stages 64-key tiles of K [64 keys][64 d] and
// V^T [64 d][64 keys] in LDS (pad +8), m97 2-barrier pattern.
// Per tile per wave:  S^T = K.Q^T (16 mfma 16x16x32, A=K from LDS, B=Q regs)
//   -> mask+exp in regs (S^T C-layout == A-frag layout of 16x16x16 mfma)
//   -> PV (32 mfma K=16, B=V from LDS) + row-sum via all-ones B (8 mfma).
// Fixed-shift softmax p=exp(s-16); shift cancels in O/l.  Longest blocks
// (high qb32) launch first.
// ---------------------------------------------------------------------------
__global__ __launch_bounds__(256)
void flash_kernel() {
    __shared__ __align__(16) bf16_t Ks[64][72];   // [key][d]
    __shared__ __align__(16) bf16_t Vs[64][72];   // [d][key]

    int t    = threadIdx.x;
    int lane = t & 63, wid = t >> 6;
    int quad = lane >> 4, l15 = lane & 15;
    int hk   = blockIdx.x & 7;
    int qb32 = 63 - (blockIdx.x >> 3);    // longest first
    int head = hk * 4 + wid;
    int q0   = qb32 * 32;

    // Q B-frags: aq[mt_q][ks]  (B[kdim=quad*8+j][n=q=l15]), pre-scaled 1/8
    bf16x8 aq[2][2];
    #pragma unroll
    for (int mq = 0; mq < 2; ++mq) {
        const bf16_t* qp = g_q + (size_t)(q0 + mq * 16 + l15) * HID + head * 64 + quad * 8;
        aq[mq][0] = *reinterpret_cast<const bf16x8*>(qp);
        aq[mq][1] = *reinterpret_cast<const bf16x8*>(qp + 32);
        #pragma unroll
        for (int j = 0; j < 8; ++j) {
            aq[mq][0][j] = (bf16_t)((float)aq[mq][0][j] * 0.125f);  // exact
            aq[mq][1][j] = (bf16_t)((float)aq[mq][1][j] * 0.125f);
        }
    }

    bf16x4 ones4;
    #pragma unroll
    for (int j = 0; j < 4; ++j) ones4[j] = (bf16_t)1.0f;
    s16x4 ones_s = bc4(ones4);

    f32x4 oacc[2][4], liacc[2];
    #pragma unroll
    for (int mq = 0; mq < 2; ++mq) {
        #pragma unroll
        for (int r = 0; r < 4; ++r) liacc[mq][r] = 0.f;
        #pragma unroll
        for (int dt = 0; dt < 4; ++dt)
            #pragma unroll
            for (int r = 0; r < 4; ++r) oacc[mq][dt][r] = 0.f;
    }

    int qcol[2] = { q0 + l15, q0 + 16 + l15 };   // this lane's q per M-tile
    int nkt = (qb32 >> 1) + 1;                    // 64-key tiles covering k <= q0+31

    for (int kt = 0; kt < nkt; ++kt) {
        int k0 = kt * 64;
        __syncthreads();
        #pragma unroll
        for (int i = t; i < 512; i += 256) {
            int row = i >> 3, seg = i & 7;
            *reinterpret_cast<int4*>(&Ks[row][seg * 8]) =
                *reinterpret_cast<const int4*>(g_k + (size_t)(k0 + row) * KVW + hk * 64 + seg * 8);
            *reinterpret_cast<int4*>(&Vs[row][seg * 8]) =
                *reinterpret_cast<const int4*>(g_vT + (size_t)(hk * 64 + row) * S_LEN + k0 + seg * 8);
        }
        __syncthreads();

        // K A-frags for this tile
        bf16x8 ak[4][2];
        #pragma unroll
        for (int mk = 0; mk < 4; ++mk) {
            ak[mk][0] = *reinterpret_cast<const bf16x8*>(&Ks[mk * 16 + l15][quad * 8]);
            ak[mk][1] = *reinterpret_cast<const bf16x8*>(&Ks[mk * 16 + l15][32 + quad * 8]);
        }

        // S^T = K . Q^T
        f32x4 sacc[4][2];
        #pragma unroll
        for (int mk = 0; mk < 4; ++mk)
            #pragma unroll
            for (int mq = 0; mq < 2; ++mq) {
                f32x4 s;
                #pragma unroll
                for (int r = 0; r < 4; ++r) s[r] = 0.f;
                s = __builtin_amdgcn_mfma_f32_16x16x32_bf16(ak[mk][0], aq[mq][0], s, 0, 0, 0);
                s = __builtin_amdgcn_mfma_f32_16x16x32_bf16(ak[mk][1], aq[mq][1], s, 0, 0, 0);
                sacc[mk][mq] = s;
            }

        // mask + exp -> P^T fragments (A-layout of K=16 mfma), in registers
        s16x4 pas[4][2];
        #pragma unroll
        for (int mk = 0; mk < 4; ++mk)
            #pragma unroll
            for (int mq = 0; mq < 2; ++mq) {
                bf16x4 pa;
                #pragma unroll
                for (int r = 0; r < 4; ++r) {
                    int kk = k0 + mk * 16 + quad * 4 + r;
                    pa[r] = (bf16_t)((kk <= qcol[mq]) ? __expf(sacc[mk][mq][r] - 16.0f) : 0.0f);
                }
                pas[mk][mq] = bc4(pa);
            }

        // PV + row-sum
        #pragma unroll
        for (int mk = 0; mk < 4; ++mk) {
            #pragma unroll
            for (int dt = 0; dt < 4; ++dt) {
                bf16x4 bv = *reinterpret_cast<const bf16x4*>(&Vs[dt * 16 + l15][mk * 16 + quad * 4]);
                s16x4 bvs = bc4(bv);
                #pragma unroll
                for (int mq = 0; mq < 2; ++mq)
                    oacc[mq][dt] = __builtin_amdgcn_mfma_f32_16x16x16bf16_1k(pas[mk][mq], bvs, oacc[mq][dt], 0, 0, 0);
            }
            #pragma unroll
            for (int mq = 0; mq < 2; ++mq)
                liacc[mq] = __builtin_amdgcn_mfma_f32_16x16x16bf16_1k(pas[mk][mq], ones_s, liacc[mq], 0, 0, 0);
        }
    }

    // O: row(q) = q0 + mq*16 + quad*4 + r, col(d) = dt*16 + l15.
    #pragma unroll
    for (int mq = 0; mq < 2; ++mq)
        #pragma unroll
        for (int r = 0; r < 4; ++r) {
            float inv = 1.0f / liacc[mq][r];
            int row = q0 + mq * 16 + quad * 4 + r;
            #pragma unroll
            for (int dt = 0; dt < 4; ++dt)
                g_om[(size_t)row * HID + head * 64 + dt * 16 + l15] = (bf16_t)(oacc[mq][dt][r] * inv);
        }
}

// ---------------------------------------------------------------------------
// Launch
// ---------------------------------------------------------------------------
extern "C" void kernel_launch(void* const* d_in, const int* in_sizes, int n_in,
                              void* d_out, int out_size, void* d_ws, size_t ws_size,
                              hipStream_t stream) {
    const float* x    = (const float*)d_in[0];
    const float* qpW  = (const float*)d_in[1];
    const float* kpW  = (const float*)d_in[2];
    const float* vpW  = (const float*)d_in[3];
    const float* opW  = (const float*)d_in[4];
    const void*  invf = d_in[5];
    float* out = (float*)d_out;

    dim3 tb(64, 4);

    rope_table_kernel<<<256, 256, 0, stream>>>(invf);
    convert_x_kernel<<<4096, 256, 0, stream>>>(x);

    // Q = rope(x @ q_proj)
    transpose_kernel<<<dim3(32, 32), tb, 0, stream>>>(qpW, HID, HID);
    gemm_bt_kernel<<<dim3(16, 16), 256, 0, stream>>>(nullptr, 0, 1, S_LEN, HID, HID, 1);
    // K = rope(x @ k_proj)
    transpose_kernel<<<dim3(8, 32), tb, 0, stream>>>(kpW, HID, KVW);
    gemm_bt_kernel<<<dim3(4, 16), 256, 0, stream>>>(nullptr, 0, 2, S_LEN, KVW, HID, 1);
    // vT = (x @ v_proj)^T
    transpose_kernel<<<dim3(8, 32), tb, 0, stream>>>(vpW, HID, KVW);
    gemm_bt_kernel<<<dim3(4, 16), 256, 0, stream>>>(nullptr, 0, 3, S_LEN, KVW, HID, 2);
    // attention: 64 qb32-blocks x 8 kv-heads
    flash_kernel<<<512, 256, 0, stream>>>();
    // out = g_om @ o_proj  (f32 store)
    transpose_kernel<<<dim3(32, 32), tb, 0, stream>>>(opW, HID, HID);
    gemm_bt_kernel<<<dim3(16, 16), 256, 0, stream>>>(out, 1, 0, S_LEN, HID, HID, 0);
}

// Round 7
// 290.649 us; speedup vs baseline: 1.9299x; 1.4065x over previous
//
#include <hip/hip_runtime.h>

// ---------------------------------------------------------------------------
// SelfAttention (GQA + nonstandard RoPE), S=2048, HIDDEN=2048, 32 q-heads,
// 8 kv-heads, D=64.  Inputs/outputs FLOAT32; internal bf16 MFMA, fp32 accum.
// R7: 4 dispatches total: prep (rope+convert+4 transposes) -> fused QKV GEMM
// -> flash (R6, unchanged) -> O GEMM.  GEMMs use global_load_lds width=16
// async staging (m97 pattern) with XOR-swizzled segments to tame LDS bank
// aliasing from the unpadded [128][32] tiles.
// ---------------------------------------------------------------------------

typedef __bf16 bf16_t;
typedef __bf16 bf16x4 __attribute__((ext_vector_type(4)));
typedef __bf16 bf16x8 __attribute__((ext_vector_type(8)));
typedef float  f32x4  __attribute__((ext_vector_type(4)));
typedef short  s16x4  __attribute__((ext_vector_type(4)));

#define S_LEN   2048
#define HID     2048
#define NKV     8
#define NH      32
#define DHEAD   64
#define KVW     (NKV * DHEAD)   // 512

// ---- module-global scratch (rewritten fully each call) ---------------------
__device__ __align__(16) bf16_t g_xb [S_LEN * HID];     // x in bf16
__device__ __align__(16) bf16_t g_wTq[HID * HID];       // q_proj^T  [N][K]
__device__ __align__(16) bf16_t g_wTk[KVW * HID];       // k_proj^T
__device__ __align__(16) bf16_t g_wTv[KVW * HID];       // v_proj^T
__device__ __align__(16) bf16_t g_wTo[HID * HID];       // o_proj^T
__device__ __align__(16) bf16_t g_q [S_LEN * HID];      // roped Q
__device__ __align__(16) bf16_t g_k [S_LEN * KVW];      // roped K
__device__ __align__(16) bf16_t g_vT[KVW * S_LEN];      // V^T [d_total][S]
__device__ __align__(16) bf16_t g_om[S_LEN * HID];      // attn out (pre o_proj)
__device__ float g_ropeC[S_LEN * 32];
__device__ float g_ropeS[S_LEN * 32];

static __device__ inline s16x4 bc4(bf16x4 v) { s16x4 r; __builtin_memcpy(&r, &v, 8); return r; }

// async 16B global -> LDS (direct-to-shared DMA).  lds base must be
// wave-uniform; data lands at base + lane*16.  g is per-lane.
__device__ __forceinline__ void gll16(void* lds, const void* g) {
    __builtin_amdgcn_global_load_lds(
        (const __attribute__((address_space(1))) void*)g,
        (__attribute__((address_space(3))) void*)lds,
        16, 0, 0);
}

// ---------------------------------------------------------------------------
// prep: one launch does (a) RoPE table (f64-exact angles; inv_freq dtype
// sniff: word0==0x3F800000 <=> f32), (b) x f32->bf16, (c) all four weight
// transposes f32 [R][C] -> bf16 [C][R].  Branch by blockIdx range.
// ---------------------------------------------------------------------------
__global__ __launch_bounds__(256)
void prep_kernel(const float* __restrict__ x,
                 const float* __restrict__ qw, const float* __restrict__ kw,
                 const float* __restrict__ vw, const float* __restrict__ ow,
                 const void* __restrict__ invf_raw) {
    __shared__ bf16_t tile[64][65];
    int b = blockIdx.x, t = threadIdx.x;

    if (b < 256) {                               // RoPE table: 65536 entries
        int idx = b * 256 + t;
        int s = idx >> 5, j = idx & 31;
        float f;
        if (*(const unsigned*)invf_raw == 0x3F800000u) {
            f = ((const float*)invf_raw)[j];
        } else {
            unsigned u = ((unsigned)((const unsigned short*)invf_raw)[j]) << 16;
            __builtin_memcpy(&f, &u, 4);
        }
        double a = (double)s * (double)f;
        g_ropeC[idx] = (float)cos(a);
        g_ropeS[idx] = (float)sin(a);
        return;
    }
    if (b < 4352) {                              // x convert: 1M float4
        int idx = (b - 256) * 256 + t;
        float4 v = reinterpret_cast<const float4*>(x)[idx];
        bf16x4 o;
        o[0] = (bf16_t)v.x; o[1] = (bf16_t)v.y; o[2] = (bf16_t)v.z; o[3] = (bf16_t)v.w;
        *reinterpret_cast<bf16x4*>(&g_xb[(size_t)idx * 4]) = o;
        return;
    }
    // transposes
    const float* in; bf16_t* outp; int R, C, tb;
    if (b < 5376)      { in = qw; outp = g_wTq; R = HID; C = HID; tb = b - 4352; }
    else if (b < 5632) { in = kw; outp = g_wTk; R = HID; C = KVW; tb = b - 5376; }
    else if (b < 5888) { in = vw; outp = g_wTv; R = HID; C = KVW; tb = b - 5632; }
    else               { in = ow; outp = g_wTo; R = HID; C = HID; tb = b - 5888; }
    int xt = C >> 6;                             // tiles along C
    int c0 = (tb % xt) * 64, r0 = (tb / xt) * 64;
    int tx = t & 63, ty = t >> 6;
    #pragma unroll
    for (int r = ty; r < 64; r += 4)
        tile[r][tx] = (bf16_t)in[(size_t)(r0 + r) * C + c0 + tx];
    __syncthreads();
    #pragma unroll
    for (int r = ty; r < 64; r += 4)
        outp[(size_t)(c0 + r) * R + r0 + tx] = tile[tx][r];
}

// ---------------------------------------------------------------------------
// Fused MFMA GEMM, m97-style staging.  C[M=2048, N] = A[2048,2048] * B,
// B held transposed [N][2048] bf16.  128x128 block tile, 4 waves 2x2,
// 64x64/wave, BK=32.  Staging: global_load_lds 16B, unpadded LDS [128][32],
// XOR-swizzled segment (seg' = seg ^ (row&3)) carried in the per-lane global
// address; reads XOR the same way.  which=0: QKV fused over blockIdx.x
// (0-15 Q+RoPE, 16-19 K+RoPE, 20-23 V transposed-store).  which=1: O, f32.
// ---------------------------------------------------------------------------
__global__ __launch_bounds__(256)
void gemm_fused_kernel(float* __restrict__ Cf, int which) {
    __shared__ __align__(16) bf16_t As[128 * 32];
    __shared__ __align__(16) bf16_t Bs[128 * 32];

    int t    = threadIdx.x;
    int lane = t & 63, wid = t >> 6;
    int quad = lane >> 4, l15 = lane & 15;
    int bx = blockIdx.x, m0 = blockIdx.y * 128;
    int wm = (wid >> 1) * 64, wn = (wid & 1) * 64;

    const bf16_t* A; const bf16_t* Bt; int n0;
    if (which == 1)      { A = g_om; Bt = g_wTo; n0 = bx * 128; }
    else {
        A = g_xb;
        if (bx < 16)      { Bt = g_wTq; n0 = bx * 128; }
        else if (bx < 20) { Bt = g_wTk; n0 = (bx - 16) * 128; }
        else              { Bt = g_wTv; n0 = (bx - 20) * 128; }
    }

    // staging geometry: chunk = 1024B = 16 rows of 32 bf16; wave w owns
    // chunks 2w,2w+1 (rows 32w..32w+31) of both A and B tiles.
    int crow = lane >> 2;                        // row within chunk
    int gseg = (lane & 3) ^ (crow & 3);          // swizzled source segment
    int sx   = (quad ^ (l15 & 3)) * 8;           // read-side swizzle offset

    f32x4 acc[4][4];
    #pragma unroll
    for (int im = 0; im < 4; ++im)
        #pragma unroll
        for (int in = 0; in < 4; ++in)
            #pragma unroll
            for (int r = 0; r < 4; ++r) acc[im][in][r] = 0.f;

    for (int kt = 0; kt < HID; kt += 32) {
        __syncthreads();
        #pragma unroll
        for (int j = 0; j < 2; ++j) {
            int c = wid * 2 + j;
            int row = c * 16 + crow;
            gll16(&As[c * 512], A  + (size_t)(m0 + row) * HID + kt + gseg * 8);
            gll16(&Bs[c * 512], Bt + (size_t)(n0 + row) * HID + kt + gseg * 8);
        }
        __syncthreads();

        bf16x8 af[4], bfr[4];
        #pragma unroll
        for (int im = 0; im < 4; ++im)
            af[im] = *reinterpret_cast<const bf16x8*>(&As[(wm + im * 16 + l15) * 32 + sx]);
        #pragma unroll
        for (int in = 0; in < 4; ++in)
            bfr[in] = *reinterpret_cast<const bf16x8*>(&Bs[(wn + in * 16 + l15) * 32 + sx]);
        #pragma unroll
        for (int im = 0; im < 4; ++im)
            #pragma unroll
            for (int in = 0; in < 4; ++in)
                acc[im][in] = __builtin_amdgcn_mfma_f32_16x16x32_bf16(af[im], bfr[in], acc[im][in], 0, 0, 0);
    }

    if (which == 1) {                            // O: f32 row-major
        #pragma unroll
        for (int im = 0; im < 4; ++im) {
            int rowb = m0 + wm + im * 16 + quad * 4;
            #pragma unroll
            for (int in = 0; in < 4; ++in) {
                int col = bx * 128 + wn + in * 16 + l15;
                #pragma unroll
                for (int r = 0; r < 4; ++r)
                    Cf[(size_t)(rowb + r) * HID + col] = acc[im][in][r];
            }
        }
    } else if (bx < 20) {                        // Q/K: RoPE epilogue -> bf16
        bf16_t* Cb; int N, colbase;
        if (bx < 16) { Cb = g_q; N = HID; colbase = bx * 128 + wn; }
        else         { Cb = g_k; N = KVW; colbase = (bx - 16) * 128 + wn; }
        // out[d] = x[d]*cos + x[d+32]*sin ; out[d+32] = x[d]*sin - x[d+32]*cos
        #pragma unroll
        for (int im = 0; im < 4; ++im) {
            #pragma unroll
            for (int r = 0; r < 4; ++r) {
                int row = m0 + wm + im * 16 + quad * 4 + r;
                #pragma unroll
                for (int in = 0; in < 2; ++in) {
                    int d = in * 16 + l15;                 // 0..31
                    float a  = acc[im][in][r];
                    float bb = acc[im][in + 2][r];
                    float cc = g_ropeC[row * 32 + d];
                    float ss = g_ropeS[row * 32 + d];
                    Cb[(size_t)row * N + colbase + d]      = (bf16_t)(a * cc + bb * ss);
                    Cb[(size_t)row * N + colbase + 32 + d] = (bf16_t)(a * ss - bb * cc);
                }
            }
        }
    } else {                                     // V: transposed store -> g_vT
        #pragma unroll
        for (int im = 0; im < 4; ++im) {
            int rowb = m0 + wm + im * 16 + quad * 4;
            #pragma unroll
            for (int in = 0; in < 4; ++in) {
                int col = (bx - 20) * 128 + wn + in * 16 + l15;
                #pragma unroll
                for (int r = 0; r < 4; ++r)
                    g_vT[(size_t)col * S_LEN + (rowb + r)] = (bf16_t)acc[im][in][r];
            }
        }
    }
}

// ---------------------------------------------------------------------------
// Flash attention (causal, GQA), block-cooperative, register-only P (R6).
// Block = 4 waves = 4 q-heads of kv-group hk; 32 queries/wave.  64-key K/V
// tiles staged in LDS; S^T = K.Q^T so P stays in registers (S^T C-layout ==
// A-frag layout of the K=16 MFMA).  Fixed-shift softmax p=exp(s-16).
// ---------------------------------------------------------------------------
__global__ __launch_bounds__(256)
void flash_kernel() {
    __shared__ __align__(16) bf16_t Ks[64][72];   // [key][d]
    __shared__ __align__(16) bf16_t Vs[64][72];   // [d][key]

    int t    = threadIdx.x;
    int lane = t & 63, wid = t >> 6;
    int quad = lane >> 4, l15 = lane & 15;
    int hk   = blockIdx.x & 7;
    int qb32 = 63 - (blockIdx.x >> 3);    // longest first
    int head = hk * 4 + wid;
    int q0   = qb32 * 32;

    bf16x8 aq[2][2];
    #pragma unroll
    for (int mq = 0; mq < 2; ++mq) {
        const bf16_t* qp = g_q + (size_t)(q0 + mq * 16 + l15) * HID + head * 64 + quad * 8;
        aq[mq][0] = *reinterpret_cast<const bf16x8*>(qp);
        aq[mq][1] = *reinterpret_cast<const bf16x8*>(qp + 32);
        #pragma unroll
        for (int j = 0; j < 8; ++j) {
            aq[mq][0][j] = (bf16_t)((float)aq[mq][0][j] * 0.125f);  // exact
            aq[mq][1][j] = (bf16_t)((float)aq[mq][1][j] * 0.125f);
        }
    }

    bf16x4 ones4;
    #pragma unroll
    for (int j = 0; j < 4; ++j) ones4[j] = (bf16_t)1.0f;
    s16x4 ones_s = bc4(ones4);

    f32x4 oacc[2][4], liacc[2];
    #pragma unroll
    for (int mq = 0; mq < 2; ++mq) {
        #pragma unroll
        for (int r = 0; r < 4; ++r) liacc[mq][r] = 0.f;
        #pragma unroll
        for (int dt = 0; dt < 4; ++dt)
            #pragma unroll
            for (int r = 0; r < 4; ++r) oacc[mq][dt][r] = 0.f;
    }

    int qcol[2] = { q0 + l15, q0 + 16 + l15 };
    int nkt = (qb32 >> 1) + 1;

    for (int kt = 0; kt < nkt; ++kt) {
        int k0 = kt * 64;
        __syncthreads();
        #pragma unroll
        for (int i = t; i < 512; i += 256) {
            int row = i >> 3, seg = i & 7;
            *reinterpret_cast<int4*>(&Ks[row][seg * 8]) =
                *reinterpret_cast<const int4*>(g_k + (size_t)(k0 + row) * KVW + hk * 64 + seg * 8);
            *reinterpret_cast<int4*>(&Vs[row][seg * 8]) =
                *reinterpret_cast<const int4*>(g_vT + (size_t)(hk * 64 + row) * S_LEN + k0 + seg * 8);
        }
        __syncthreads();

        bf16x8 ak[4][2];
        #pragma unroll
        for (int mk = 0; mk < 4; ++mk) {
            ak[mk][0] = *reinterpret_cast<const bf16x8*>(&Ks[mk * 16 + l15][quad * 8]);
            ak[mk][1] = *reinterpret_cast<const bf16x8*>(&Ks[mk * 16 + l15][32 + quad * 8]);
        }

        f32x4 sacc[4][2];
        #pragma unroll
        for (int mk = 0; mk < 4; ++mk)
            #pragma unroll
            for (int mq = 0; mq < 2; ++mq) {
                f32x4 s;
                #pragma unroll
                for (int r = 0; r < 4; ++r) s[r] = 0.f;
                s = __builtin_amdgcn_mfma_f32_16x16x32_bf16(ak[mk][0], aq[mq][0], s, 0, 0, 0);
                s = __builtin_amdgcn_mfma_f32_16x16x32_bf16(ak[mk][1], aq[mq][1], s, 0, 0, 0);
                sacc[mk][mq] = s;
            }

        s16x4 pas[4][2];
        #pragma unroll
        for (int mk = 0; mk < 4; ++mk)
            #pragma unroll
            for (int mq = 0; mq < 2; ++mq) {
                bf16x4 pa;
                #pragma unroll
                for (int r = 0; r < 4; ++r) {
                    int kk = k0 + mk * 16 + quad * 4 + r;
                    pa[r] = (bf16_t)((kk <= qcol[mq]) ? __expf(sacc[mk][mq][r] - 16.0f) : 0.0f);
                }
                pas[mk][mq] = bc4(pa);
            }

        #pragma unroll
        for (int mk = 0; mk < 4; ++mk) {
            #pragma unroll
            for (int dt = 0; dt < 4; ++dt) {
                bf16x4 bv = *reinterpret_cast<const bf16x4*>(&Vs[dt * 16 + l15][mk * 16 + quad * 4]);
                s16x4 bvs = bc4(bv);
                #pragma unroll
                for (int mq = 0; mq < 2; ++mq)
                    oacc[mq][dt] = __builtin_amdgcn_mfma_f32_16x16x16bf16_1k(pas[mk][mq], bvs, oacc[mq][dt], 0, 0, 0);
            }
            #pragma unroll
            for (int mq = 0; mq < 2; ++mq)
                liacc[mq] = __builtin_amdgcn_mfma_f32_16x16x16bf16_1k(pas[mk][mq], ones_s, liacc[mq], 0, 0, 0);
        }
    }

    #pragma unroll
    for (int mq = 0; mq < 2; ++mq)
        #pragma unroll
        for (int r = 0; r < 4; ++r) {
            float inv = 1.0f / liacc[mq][r];
            int row = q0 + mq * 16 + quad * 4 + r;
            #pragma unroll
            for (int dt = 0; dt < 4; ++dt)
                g_om[(size_t)row * HID + head * 64 + dt * 16 + l15] = (bf16_t)(oacc[mq][dt][r] * inv);
        }
}

// ---------------------------------------------------------------------------
// Launch: 4 dispatches.
// ---------------------------------------------------------------------------
extern "C" void kernel_launch(void* const* d_in, const int* in_sizes, int n_in,
                              void* d_out, int out_size, void* d_ws, size_t ws_size,
                              hipStream_t stream) {
    const float* x    = (const float*)d_in[0];
    const float* qpW  = (const float*)d_in[1];
    const float* kpW  = (const float*)d_in[2];
    const float* vpW  = (const float*)d_in[3];
    const float* opW  = (const float*)d_in[4];
    const void*  invf = d_in[5];
    float* out = (float*)d_out;

    prep_kernel<<<6912, 256, 0, stream>>>(x, qpW, kpW, vpW, opW, invf);
    gemm_fused_kernel<<<dim3(24, 16), 256, 0, stream>>>(nullptr, 0);   // QKV
    flash_kernel<<<512, 256, 0, stream>>>();
    gemm_fused_kernel<<<dim3(16, 16), 256, 0, stream>>>(out, 1);       // O
}

// Round 8
// 282.772 us; speedup vs baseline: 1.9837x; 1.0279x over previous
//
#include <hip/hip_runtime.h>

// ---------------------------------------------------------------------------
// SelfAttention (GQA + nonstandard RoPE), S=2048, HIDDEN=2048, 32 q-heads,
// 8 kv-heads, D=64.  Inputs/outputs FLOAT32; internal bf16 MFMA, fp32 accum.
// R8: GEMM block tile 128x128 -> 64x128 (waves 2x2, 32x64 each) to lift
// blocks/CU from 1.5/1.0 to 3/2 — the m97 overlap needs >=2 co-resident
// blocks.  Everything else (prep, flash) unchanged from R7.
// ---------------------------------------------------------------------------

typedef __bf16 bf16_t;
typedef __bf16 bf16x4 __attribute__((ext_vector_type(4)));
typedef __bf16 bf16x8 __attribute__((ext_vector_type(8)));
typedef float  f32x4  __attribute__((ext_vector_type(4)));
typedef short  s16x4  __attribute__((ext_vector_type(4)));

#define S_LEN   2048
#define HID     2048
#define NKV     8
#define NH      32
#define DHEAD   64
#define KVW     (NKV * DHEAD)   // 512

// ---- module-global scratch (rewritten fully each call) ---------------------
__device__ __align__(16) bf16_t g_xb [S_LEN * HID];     // x in bf16
__device__ __align__(16) bf16_t g_wTq[HID * HID];       // q_proj^T  [N][K]
__device__ __align__(16) bf16_t g_wTk[KVW * HID];       // k_proj^T
__device__ __align__(16) bf16_t g_wTv[KVW * HID];       // v_proj^T
__device__ __align__(16) bf16_t g_wTo[HID * HID];       // o_proj^T
__device__ __align__(16) bf16_t g_q [S_LEN * HID];      // roped Q
__device__ __align__(16) bf16_t g_k [S_LEN * KVW];      // roped K
__device__ __align__(16) bf16_t g_vT[KVW * S_LEN];      // V^T [d_total][S]
__device__ __align__(16) bf16_t g_om[S_LEN * HID];      // attn out (pre o_proj)
__device__ float g_ropeC[S_LEN * 32];
__device__ float g_ropeS[S_LEN * 32];

static __device__ inline s16x4 bc4(bf16x4 v) { s16x4 r; __builtin_memcpy(&r, &v, 8); return r; }

// async 16B global -> LDS.  lds base wave-uniform; data lands at base+lane*16.
__device__ __forceinline__ void gll16(void* lds, const void* g) {
    __builtin_amdgcn_global_load_lds(
        (const __attribute__((address_space(1))) void*)g,
        (__attribute__((address_space(3))) void*)lds,
        16, 0, 0);
}

// ---------------------------------------------------------------------------
// prep: (a) RoPE table (f64-exact; inv_freq dtype sniff), (b) x f32->bf16,
// (c) four weight transposes f32 [R][C] -> bf16 [C][R].
// ---------------------------------------------------------------------------
__global__ __launch_bounds__(256)
void prep_kernel(const float* __restrict__ x,
                 const float* __restrict__ qw, const float* __restrict__ kw,
                 const float* __restrict__ vw, const float* __restrict__ ow,
                 const void* __restrict__ invf_raw) {
    __shared__ bf16_t tile[64][65];
    int b = blockIdx.x, t = threadIdx.x;

    if (b < 256) {                               // RoPE table: 65536 entries
        int idx = b * 256 + t;
        int s = idx >> 5, j = idx & 31;
        float f;
        if (*(const unsigned*)invf_raw == 0x3F800000u) {
            f = ((const float*)invf_raw)[j];
        } else {
            unsigned u = ((unsigned)((const unsigned short*)invf_raw)[j]) << 16;
            __builtin_memcpy(&f, &u, 4);
        }
        double a = (double)s * (double)f;
        g_ropeC[idx] = (float)cos(a);
        g_ropeS[idx] = (float)sin(a);
        return;
    }
    if (b < 4352) {                              // x convert: 1M float4
        int idx = (b - 256) * 256 + t;
        float4 v = reinterpret_cast<const float4*>(x)[idx];
        bf16x4 o;
        o[0] = (bf16_t)v.x; o[1] = (bf16_t)v.y; o[2] = (bf16_t)v.z; o[3] = (bf16_t)v.w;
        *reinterpret_cast<bf16x4*>(&g_xb[(size_t)idx * 4]) = o;
        return;
    }
    const float* in; bf16_t* outp; int R, C, tb;
    if (b < 5376)      { in = qw; outp = g_wTq; R = HID; C = HID; tb = b - 4352; }
    else if (b < 5632) { in = kw; outp = g_wTk; R = HID; C = KVW; tb = b - 5376; }
    else if (b < 5888) { in = vw; outp = g_wTv; R = HID; C = KVW; tb = b - 5632; }
    else               { in = ow; outp = g_wTo; R = HID; C = HID; tb = b - 5888; }
    int xt = C >> 6;
    int c0 = (tb % xt) * 64, r0 = (tb / xt) * 64;
    int tx = t & 63, ty = t >> 6;
    #pragma unroll
    for (int r = ty; r < 64; r += 4)
        tile[r][tx] = (bf16_t)in[(size_t)(r0 + r) * C + c0 + tx];
    __syncthreads();
    #pragma unroll
    for (int r = ty; r < 64; r += 4)
        outp[(size_t)(c0 + r) * R + r0 + tx] = tile[tx][r];
}

// ---------------------------------------------------------------------------
// Fused MFMA GEMM, m97-style staging, 64x128 block tile.
// C[M=2048, N] = A[2048,2048] * B,  B transposed [N][2048] bf16.
// 4 waves 2x2, each wave 32x64 (2x4 mfma tiles), BK=32.
// Staging: global_load_lds 16B into unpadded LDS [rows][32], XOR-swizzled
// segment (seg' = seg ^ (row&3)) in the per-lane global address; reads XOR
// identically.  which=0: QKV fused over bx (0-15 Q+RoPE, 16-19 K+RoPE,
// 20-23 V transposed).  which=1: O, f32 out.
// ---------------------------------------------------------------------------
__global__ __launch_bounds__(256)
void gemm_fused_kernel(float* __restrict__ Cf, int which) {
    __shared__ __align__(16) bf16_t As[64 * 32];    // 4 chunks of 16 rows
    __shared__ __align__(16) bf16_t Bs[128 * 32];   // 8 chunks

    int t    = threadIdx.x;
    int lane = t & 63, wid = t >> 6;
    int quad = lane >> 4, l15 = lane & 15;
    int bx = blockIdx.x, m0 = blockIdx.y * 64;
    int wm = (wid >> 1) * 32, wn = (wid & 1) * 64;

    const bf16_t* A; const bf16_t* Bt; int n0;
    if (which == 1)      { A = g_om; Bt = g_wTo; n0 = bx * 128; }
    else {
        A = g_xb;
        if (bx < 16)      { Bt = g_wTq; n0 = bx * 128; }
        else if (bx < 20) { Bt = g_wTk; n0 = (bx - 16) * 128; }
        else              { Bt = g_wTv; n0 = (bx - 20) * 128; }
    }

    // staging geometry: chunk = 16 rows x 32 bf16 = 1024B = 64 lanes x 16B.
    int crow = lane >> 2;                        // row within chunk
    int gseg = (lane & 3) ^ (crow & 3);          // swizzled source segment
    int sx   = (quad ^ (l15 & 3)) * 8;           // read-side swizzle offset

    f32x4 acc[2][4];
    #pragma unroll
    for (int im = 0; im < 2; ++im)
        #pragma unroll
        for (int in = 0; in < 4; ++in)
            #pragma unroll
            for (int r = 0; r < 4; ++r) acc[im][in][r] = 0.f;

    for (int kt = 0; kt < HID; kt += 32) {
        __syncthreads();
        // wave w stages As chunk w, Bs chunks 2w and 2w+1
        gll16(&As[wid * 512],           A  + (size_t)(m0 + wid * 16 + crow) * HID + kt + gseg * 8);
        gll16(&Bs[(wid * 2) * 512],     Bt + (size_t)(n0 + wid * 32 + crow) * HID + kt + gseg * 8);
        gll16(&Bs[(wid * 2 + 1) * 512], Bt + (size_t)(n0 + wid * 32 + 16 + crow) * HID + kt + gseg * 8);
        __syncthreads();

        bf16x8 af[2], bfr[4];
        #pragma unroll
        for (int im = 0; im < 2; ++im)
            af[im] = *reinterpret_cast<const bf16x8*>(&As[(wm + im * 16 + l15) * 32 + sx]);
        #pragma unroll
        for (int in = 0; in < 4; ++in)
            bfr[in] = *reinterpret_cast<const bf16x8*>(&Bs[(wn + in * 16 + l15) * 32 + sx]);
        #pragma unroll
        for (int im = 0; im < 2; ++im)
            #pragma unroll
            for (int in = 0; in < 4; ++in)
                acc[im][in] = __builtin_amdgcn_mfma_f32_16x16x32_bf16(af[im], bfr[in], acc[im][in], 0, 0, 0);
    }

    if (which == 1) {                            // O: f32 row-major
        #pragma unroll
        for (int im = 0; im < 2; ++im) {
            int rowb = m0 + wm + im * 16 + quad * 4;
            #pragma unroll
            for (int in = 0; in < 4; ++in) {
                int col = bx * 128 + wn + in * 16 + l15;
                #pragma unroll
                for (int r = 0; r < 4; ++r)
                    Cf[(size_t)(rowb + r) * HID + col] = acc[im][in][r];
            }
        }
    } else if (bx < 20) {                        // Q/K: RoPE epilogue -> bf16
        bf16_t* Cb; int N, colbase;
        if (bx < 16) { Cb = g_q; N = HID; colbase = bx * 128 + wn; }
        else         { Cb = g_k; N = KVW; colbase = (bx - 16) * 128 + wn; }
        // out[d] = x[d]*cos + x[d+32]*sin ; out[d+32] = x[d]*sin - x[d+32]*cos
        #pragma unroll
        for (int im = 0; im < 2; ++im) {
            #pragma unroll
            for (int r = 0; r < 4; ++r) {
                int row = m0 + wm + im * 16 + quad * 4 + r;
                #pragma unroll
                for (int in = 0; in < 2; ++in) {
                    int d = in * 16 + l15;                 // 0..31
                    float a  = acc[im][in][r];
                    float bb = acc[im][in + 2][r];
                    float cc = g_ropeC[row * 32 + d];
                    float ss = g_ropeS[row * 32 + d];
                    Cb[(size_t)row * N + colbase + d]      = (bf16_t)(a * cc + bb * ss);
                    Cb[(size_t)row * N + colbase + 32 + d] = (bf16_t)(a * ss - bb * cc);
                }
            }
        }
    } else {                                     // V: transposed store -> g_vT
        #pragma unroll
        for (int im = 0; im < 2; ++im) {
            int rowb = m0 + wm + im * 16 + quad * 4;
            #pragma unroll
            for (int in = 0; in < 4; ++in) {
                int col = (bx - 20) * 128 + wn + in * 16 + l15;
                #pragma unroll
                for (int r = 0; r < 4; ++r)
                    g_vT[(size_t)col * S_LEN + (rowb + r)] = (bf16_t)acc[im][in][r];
            }
        }
    }
}

// ---------------------------------------------------------------------------
// Flash attention (causal, GQA), block-cooperative, register-only P (R6).
// Block = 4 waves = 4 q-heads of kv-group hk; 32 queries/wave.  64-key K/V
// tiles staged in LDS; S^T = K.Q^T so P stays in registers (S^T C-layout ==
// A-frag layout of the K=16 MFMA).  Fixed-shift softmax p=exp(s-16).
// ---------------------------------------------------------------------------
__global__ __launch_bounds__(256)
void flash_kernel() {
    __shared__ __align__(16) bf16_t Ks[64][72];   // [key][d]
    __shared__ __align__(16) bf16_t Vs[64][72];   // [d][key]

    int t    = threadIdx.x;
    int lane = t & 63, wid = t >> 6;
    int quad = lane >> 4, l15 = lane & 15;
    int hk   = blockIdx.x & 7;
    int qb32 = 63 - (blockIdx.x >> 3);    // longest first
    int head = hk * 4 + wid;
    int q0   = qb32 * 32;

    bf16x8 aq[2][2];
    #pragma unroll
    for (int mq = 0; mq < 2; ++mq) {
        const bf16_t* qp = g_q + (size_t)(q0 + mq * 16 + l15) * HID + head * 64 + quad * 8;
        aq[mq][0] = *reinterpret_cast<const bf16x8*>(qp);
        aq[mq][1] = *reinterpret_cast<const bf16x8*>(qp + 32);
        #pragma unroll
        for (int j = 0; j < 8; ++j) {
            aq[mq][0][j] = (bf16_t)((float)aq[mq][0][j] * 0.125f);  // exact
            aq[mq][1][j] = (bf16_t)((float)aq[mq][1][j] * 0.125f);
        }
    }

    bf16x4 ones4;
    #pragma unroll
    for (int j = 0; j < 4; ++j) ones4[j] = (bf16_t)1.0f;
    s16x4 ones_s = bc4(ones4);

    f32x4 oacc[2][4], liacc[2];
    #pragma unroll
    for (int mq = 0; mq < 2; ++mq) {
        #pragma unroll
        for (int r = 0; r < 4; ++r) liacc[mq][r] = 0.f;
        #pragma unroll
        for (int dt = 0; dt < 4; ++dt)
            #pragma unroll
            for (int r = 0; r < 4; ++r) oacc[mq][dt][r] = 0.f;
    }

    int qcol[2] = { q0 + l15, q0 + 16 + l15 };
    int nkt = (qb32 >> 1) + 1;

    for (int kt = 0; kt < nkt; ++kt) {
        int k0 = kt * 64;
        __syncthreads();
        #pragma unroll
        for (int i = t; i < 512; i += 256) {
            int row = i >> 3, seg = i & 7;
            *reinterpret_cast<int4*>(&Ks[row][seg * 8]) =
                *reinterpret_cast<const int4*>(g_k + (size_t)(k0 + row) * KVW + hk * 64 + seg * 8);
            *reinterpret_cast<int4*>(&Vs[row][seg * 8]) =
                *reinterpret_cast<const int4*>(g_vT + (size_t)(hk * 64 + row) * S_LEN + k0 + seg * 8);
        }
        __syncthreads();

        bf16x8 ak[4][2];
        #pragma unroll
        for (int mk = 0; mk < 4; ++mk) {
            ak[mk][0] = *reinterpret_cast<const bf16x8*>(&Ks[mk * 16 + l15][quad * 8]);
            ak[mk][1] = *reinterpret_cast<const bf16x8*>(&Ks[mk * 16 + l15][32 + quad * 8]);
        }

        f32x4 sacc[4][2];
        #pragma unroll
        for (int mk = 0; mk < 4; ++mk)
            #pragma unroll
            for (int mq = 0; mq < 2; ++mq) {
                f32x4 s;
                #pragma unroll
                for (int r = 0; r < 4; ++r) s[r] = 0.f;
                s = __builtin_amdgcn_mfma_f32_16x16x32_bf16(ak[mk][0], aq[mq][0], s, 0, 0, 0);
                s = __builtin_amdgcn_mfma_f32_16x16x32_bf16(ak[mk][1], aq[mq][1], s, 0, 0, 0);
                sacc[mk][mq] = s;
            }

        s16x4 pas[4][2];
        #pragma unroll
        for (int mk = 0; mk < 4; ++mk)
            #pragma unroll
            for (int mq = 0; mq < 2; ++mq) {
                bf16x4 pa;
                #pragma unroll
                for (int r = 0; r < 4; ++r) {
                    int kk = k0 + mk * 16 + quad * 4 + r;
                    pa[r] = (bf16_t)((kk <= qcol[mq]) ? __expf(sacc[mk][mq][r] - 16.0f) : 0.0f);
                }
                pas[mk][mq] = bc4(pa);
            }

        #pragma unroll
        for (int mk = 0; mk < 4; ++mk) {
            #pragma unroll
            for (int dt = 0; dt < 4; ++dt) {
                bf16x4 bv = *reinterpret_cast<const bf16x4*>(&Vs[dt * 16 + l15][mk * 16 + quad * 4]);
                s16x4 bvs = bc4(bv);
                #pragma unroll
                for (int mq = 0; mq < 2; ++mq)
                    oacc[mq][dt] = __builtin_amdgcn_mfma_f32_16x16x16bf16_1k(pas[mk][mq], bvs, oacc[mq][dt], 0, 0, 0);
            }
            #pragma unroll
            for (int mq = 0; mq < 2; ++mq)
                liacc[mq] = __builtin_amdgcn_mfma_f32_16x16x16bf16_1k(pas[mk][mq], ones_s, liacc[mq], 0, 0, 0);
        }
    }

    #pragma unroll
    for (int mq = 0; mq < 2; ++mq)
        #pragma unroll
        for (int r = 0; r < 4; ++r) {
            float inv = 1.0f / liacc[mq][r];
            int row = q0 + mq * 16 + quad * 4 + r;
            #pragma unroll
            for (int dt = 0; dt < 4; ++dt)
                g_om[(size_t)row * HID + head * 64 + dt * 16 + l15] = (bf16_t)(oacc[mq][dt][r] * inv);
        }
}

// ---------------------------------------------------------------------------
// Launch: 4 dispatches.
// ---------------------------------------------------------------------------
extern "C" void kernel_launch(void* const* d_in, const int* in_sizes, int n_in,
                              void* d_out, int out_size, void* d_ws, size_t ws_size,
                              hipStream_t stream) {
    const float* x    = (const float*)d_in[0];
    const float* qpW  = (const float*)d_in[1];
    const float* kpW  = (const float*)d_in[2];
    const float* vpW  = (const float*)d_in[3];
    const float* opW  = (const float*)d_in[4];
    const void*  invf = d_in[5];
    float* out = (float*)d_out;

    prep_kernel<<<6912, 256, 0, stream>>>(x, qpW, kpW, vpW, opW, invf);
    gemm_fused_kernel<<<dim3(24, 32), 256, 0, stream>>>(nullptr, 0);   // QKV
    flash_kernel<<<512, 256, 0, stream>>>();
    gemm_fused_kernel<<<dim3(16, 32), 256, 0, stream>>>(out, 1);       // O
}

// Round 10
// 258.225 us; speedup vs baseline: 2.1722x; 1.0951x over previous
//
#include <hip/hip_runtime.h>

// ---------------------------------------------------------------------------
// SelfAttention (GQA + nonstandard RoPE), S=2048, HIDDEN=2048, 32 q-heads,
// 8 kv-heads, D=64.  Inputs/outputs FLOAT32; internal bf16 MFMA, fp32 accum.
// R9b: GEMM K-loop restructured: BK=64 + double-buffered LDS (48 KB), loads
// for tile t+1 issued AFTER the barrier and in flight during compute of t.
// Mod-8 XOR segment swizzle (global-address side) keeps LDS reads 2-way.
// (R9 resubmission: STAGE macro -> inline lambda, no #pragma-in-macro.)
// Flash & prep unchanged from R8.
// ---------------------------------------------------------------------------

typedef __bf16 bf16_t;
typedef __bf16 bf16x4 __attribute__((ext_vector_type(4)));
typedef __bf16 bf16x8 __attribute__((ext_vector_type(8)));
typedef float  f32x4  __attribute__((ext_vector_type(4)));
typedef short  s16x4  __attribute__((ext_vector_type(4)));

#define S_LEN   2048
#define HID     2048
#define NKV     8
#define NH      32
#define DHEAD   64
#define KVW     (NKV * DHEAD)   // 512

// ---- module-global scratch (rewritten fully each call) ---------------------
__device__ __align__(16) bf16_t g_xb [S_LEN * HID];     // x in bf16
__device__ __align__(16) bf16_t g_wTq[HID * HID];       // q_proj^T  [N][K]
__device__ __align__(16) bf16_t g_wTk[KVW * HID];       // k_proj^T
__device__ __align__(16) bf16_t g_wTv[KVW * HID];       // v_proj^T
__device__ __align__(16) bf16_t g_wTo[HID * HID];       // o_proj^T
__device__ __align__(16) bf16_t g_q [S_LEN * HID];      // roped Q
__device__ __align__(16) bf16_t g_k [S_LEN * KVW];      // roped K
__device__ __align__(16) bf16_t g_vT[KVW * S_LEN];      // V^T [d_total][S]
__device__ __align__(16) bf16_t g_om[S_LEN * HID];      // attn out (pre o_proj)
__device__ float g_ropeC[S_LEN * 32];
__device__ float g_ropeS[S_LEN * 32];

static __device__ inline s16x4 bc4(bf16x4 v) { s16x4 r; __builtin_memcpy(&r, &v, 8); return r; }

// async 16B global -> LDS.  lds base wave-uniform; data lands at base+lane*16.
__device__ __forceinline__ void gll16(void* lds, const void* g) {
    __builtin_amdgcn_global_load_lds(
        (const __attribute__((address_space(1))) void*)g,
        (__attribute__((address_space(3))) void*)lds,
        16, 0, 0);
}

// ---------------------------------------------------------------------------
// prep: (a) RoPE table (f64-exact; inv_freq dtype sniff), (b) x f32->bf16,
// (c) four weight transposes f32 [R][C] -> bf16 [C][R].
// ---------------------------------------------------------------------------
__global__ __launch_bounds__(256)
void prep_kernel(const float* __restrict__ x,
                 const float* __restrict__ qw, const float* __restrict__ kw,
                 const float* __restrict__ vw, const float* __restrict__ ow,
                 const void* __restrict__ invf_raw) {
    __shared__ bf16_t tile[64][65];
    int b = blockIdx.x, t = threadIdx.x;

    if (b < 256) {                               // RoPE table: 65536 entries
        int idx = b * 256 + t;
        int s = idx >> 5, j = idx & 31;
        float f;
        if (*(const unsigned*)invf_raw == 0x3F800000u) {
            f = ((const float*)invf_raw)[j];
        } else {
            unsigned u = ((unsigned)((const unsigned short*)invf_raw)[j]) << 16;
            __builtin_memcpy(&f, &u, 4);
        }
        double a = (double)s * (double)f;
        g_ropeC[idx] = (float)cos(a);
        g_ropeS[idx] = (float)sin(a);
        return;
    }
    if (b < 4352) {                              // x convert: 1M float4
        int idx = (b - 256) * 256 + t;
        float4 v = reinterpret_cast<const float4*>(x)[idx];
        bf16x4 o;
        o[0] = (bf16_t)v.x; o[1] = (bf16_t)v.y; o[2] = (bf16_t)v.z; o[3] = (bf16_t)v.w;
        *reinterpret_cast<bf16x4*>(&g_xb[(size_t)idx * 4]) = o;
        return;
    }
    const float* in; bf16_t* outp; int R, C, tb;
    if (b < 5376)      { in = qw; outp = g_wTq; R = HID; C = HID; tb = b - 4352; }
    else if (b < 5632) { in = kw; outp = g_wTk; R = HID; C = KVW; tb = b - 5376; }
    else if (b < 5888) { in = vw; outp = g_wTv; R = HID; C = KVW; tb = b - 5632; }
    else               { in = ow; outp = g_wTo; R = HID; C = HID; tb = b - 5888; }
    int xt = C >> 6;
    int c0 = (tb % xt) * 64, r0 = (tb / xt) * 64;
    int tx = t & 63, ty = t >> 6;
    #pragma unroll
    for (int r = ty; r < 64; r += 4)
        tile[r][tx] = (bf16_t)in[(size_t)(r0 + r) * C + c0 + tx];
    __syncthreads();
    #pragma unroll
    for (int r = ty; r < 64; r += 4)
        outp[(size_t)(c0 + r) * R + r0 + tx] = tile[tx][r];
}

// ---------------------------------------------------------------------------
// Fused MFMA GEMM, 64x128 block tile, BK=64, double-buffered LDS.
// C[M=2048, N] = A[2048,2048] * B,  B transposed [N][2048] bf16.
// 4 waves 2x2, wave-tile 32x64; per K-iter 16 MFMA + 12 ds_read_b128 +
// 6 gll16 (issued for tile t+1 right after the barrier -> in flight during
// compute of tile t).  Chunk = 8 rows x 64 bf16 = 1 KB; logical 16B octet o
// of row r lives at physical octet o^(r&7) (swizzle on the global address).
// which=0: QKV fused over bx (0-15 Q+RoPE, 16-19 K+RoPE, 20-23 V transp).
// which=1: O, f32 out.
// ---------------------------------------------------------------------------
__global__ __launch_bounds__(256)
void gemm_fused_kernel(float* __restrict__ Cf, int which) {
    __shared__ __align__(16) bf16_t As[2][64 * 64];     // 8 chunks / buf
    __shared__ __align__(16) bf16_t Bs[2][128 * 64];    // 16 chunks / buf

    int t    = threadIdx.x;
    int lane = t & 63, wid = t >> 6;
    int quad = lane >> 4, l15 = lane & 15;
    int bx = blockIdx.x, m0 = blockIdx.y * 64;
    int wm = (wid >> 1) * 32, wn = (wid & 1) * 64;

    const bf16_t* A; const bf16_t* Bt; int n0;
    if (which == 1)      { A = g_om; Bt = g_wTo; n0 = bx * 128; }
    else {
        A = g_xb;
        if (bx < 16)      { Bt = g_wTq; n0 = bx * 128; }
        else if (bx < 20) { Bt = g_wTk; n0 = (bx - 16) * 128; }
        else              { Bt = g_wTv; n0 = (bx - 20) * 128; }
    }

    int crow = lane >> 3;                        // row within 8-row chunk
    int gseg = (lane & 7) ^ crow;                // swizzled 16B source octet
    int so   = l15 & 7;                          // read-side row swizzle key

    f32x4 acc[2][4];
    #pragma unroll
    for (int im = 0; im < 2; ++im)
        #pragma unroll
        for (int in = 0; in < 4; ++in)
            #pragma unroll
            for (int r = 0; r < 4; ++r) acc[im][in][r] = 0.f;

    // staging: wave w stages A chunks 2w,2w+1 and B chunks 4w..4w+3.
    auto stage = [&](int buf, int kt) {
        int ca0 = wid * 2, cb0 = wid * 4;
        gll16(&As[buf][(ca0 + 0) * 512], A  + (size_t)(m0 + (ca0 + 0) * 8 + crow) * HID + kt + gseg * 8);
        gll16(&As[buf][(ca0 + 1) * 512], A  + (size_t)(m0 + (ca0 + 1) * 8 + crow) * HID + kt + gseg * 8);
        gll16(&Bs[buf][(cb0 + 0) * 512], Bt + (size_t)(n0 + (cb0 + 0) * 8 + crow) * HID + kt + gseg * 8);
        gll16(&Bs[buf][(cb0 + 1) * 512], Bt + (size_t)(n0 + (cb0 + 1) * 8 + crow) * HID + kt + gseg * 8);
        gll16(&Bs[buf][(cb0 + 2) * 512], Bt + (size_t)(n0 + (cb0 + 2) * 8 + crow) * HID + kt + gseg * 8);
        gll16(&Bs[buf][(cb0 + 3) * 512], Bt + (size_t)(n0 + (cb0 + 3) * 8 + crow) * HID + kt + gseg * 8);
    };

    stage(0, 0);                                  // preload buf 0

    for (int it = 0; it < 32; ++it) {
        int cur = it & 1;
        __syncthreads();                          // buf[cur] ready; buf[1-cur] free
        if (it + 1 < 32)
            stage(cur ^ 1, (it + 1) * 64);        // in flight during compute

        bf16x8 af[2][2], bfr[4][2];
        #pragma unroll
        for (int im = 0; im < 2; ++im)
            #pragma unroll
            for (int kh = 0; kh < 2; ++kh)
                af[im][kh] = *reinterpret_cast<const bf16x8*>(
                    &As[cur][(wm + im * 16 + l15) * 64 + (((kh * 4 + quad) ^ so) * 8)]);
        #pragma unroll
        for (int in = 0; in < 4; ++in)
            #pragma unroll
            for (int kh = 0; kh < 2; ++kh)
                bfr[in][kh] = *reinterpret_cast<const bf16x8*>(
                    &Bs[cur][(wn + in * 16 + l15) * 64 + (((kh * 4 + quad) ^ so) * 8)]);
        #pragma unroll
        for (int im = 0; im < 2; ++im)
            #pragma unroll
            for (int in = 0; in < 4; ++in)
                #pragma unroll
                for (int kh = 0; kh < 2; ++kh)
                    acc[im][in] = __builtin_amdgcn_mfma_f32_16x16x32_bf16(
                        af[im][kh], bfr[in][kh], acc[im][in], 0, 0, 0);
    }

    if (which == 1) {                            // O: f32 row-major
        #pragma unroll
        for (int im = 0; im < 2; ++im) {
            int rowb = m0 + wm + im * 16 + quad * 4;
            #pragma unroll
            for (int in = 0; in < 4; ++in) {
                int col = bx * 128 + wn + in * 16 + l15;
                #pragma unroll
                for (int r = 0; r < 4; ++r)
                    Cf[(size_t)(rowb + r) * HID + col] = acc[im][in][r];
            }
        }
    } else if (bx < 20) {                        // Q/K: RoPE epilogue -> bf16
        bf16_t* Cb; int N, colbase;
        if (bx < 16) { Cb = g_q; N = HID; colbase = bx * 128 + wn; }
        else         { Cb = g_k; N = KVW; colbase = (bx - 16) * 128 + wn; }
        // out[d] = x[d]*cos + x[d+32]*sin ; out[d+32] = x[d]*sin - x[d+32]*cos
        #pragma unroll
        for (int im = 0; im < 2; ++im) {
            #pragma unroll
            for (int r = 0; r < 4; ++r) {
                int row = m0 + wm + im * 16 + quad * 4 + r;
                #pragma unroll
                for (int in = 0; in < 2; ++in) {
                    int d = in * 16 + l15;                 // 0..31
                    float a  = acc[im][in][r];
                    float bb = acc[im][in + 2][r];
                    float cc = g_ropeC[row * 32 + d];
                    float ss = g_ropeS[row * 32 + d];
                    Cb[(size_t)row * N + colbase + d]      = (bf16_t)(a * cc + bb * ss);
                    Cb[(size_t)row * N + colbase + 32 + d] = (bf16_t)(a * ss - bb * cc);
                }
            }
        }
    } else {                                     // V: transposed store -> g_vT
        #pragma unroll
        for (int im = 0; im < 2; ++im) {
            int rowb = m0 + wm + im * 16 + quad * 4;
            #pragma unroll
            for (int in = 0; in < 4; ++in) {
                int col = (bx - 20) * 128 + wn + in * 16 + l15;
                #pragma unroll
                for (int r = 0; r < 4; ++r)
                    g_vT[(size_t)col * S_LEN + (rowb + r)] = (bf16_t)acc[im][in][r];
            }
        }
    }
}

// ---------------------------------------------------------------------------
// Flash attention (causal, GQA), block-cooperative, register-only P (R6).
// Block = 4 waves = 4 q-heads of kv-group hk; 32 queries/wave.  64-key K/V
// tiles staged in LDS; S^T = K.Q^T so P stays in registers (S^T C-layout ==
// A-frag layout of the K=16 MFMA).  Fixed-shift softmax p=exp(s-16).
// ---------------------------------------------------------------------------
__global__ __launch_bounds__(256)
void flash_kernel() {
    __shared__ __align__(16) bf16_t Ks[64][72];   // [key][d]
    __shared__ __align__(16) bf16_t Vs[64][72];   // [d][key]

    int t    = threadIdx.x;
    int lane = t & 63, wid = t >> 6;
    int quad = lane >> 4, l15 = lane & 15;
    int hk   = blockIdx.x & 7;
    int qb32 = 63 - (blockIdx.x >> 3);    // longest first
    int head = hk * 4 + wid;
    int q0   = qb32 * 32;

    bf16x8 aq[2][2];
    #pragma unroll
    for (int mq = 0; mq < 2; ++mq) {
        const bf16_t* qp = g_q + (size_t)(q0 + mq * 16 + l15) * HID + head * 64 + quad * 8;
        aq[mq][0] = *reinterpret_cast<const bf16x8*>(qp);
        aq[mq][1] = *reinterpret_cast<const bf16x8*>(qp + 32);
        #pragma unroll
        for (int j = 0; j < 8; ++j) {
            aq[mq][0][j] = (bf16_t)((float)aq[mq][0][j] * 0.125f);  // exact
            aq[mq][1][j] = (bf16_t)((float)aq[mq][1][j] * 0.125f);
        }
    }

    bf16x4 ones4;
    #pragma unroll
    for (int j = 0; j < 4; ++j) ones4[j] = (bf16_t)1.0f;
    s16x4 ones_s = bc4(ones4);

    f32x4 oacc[2][4], liacc[2];
    #pragma unroll
    for (int mq = 0; mq < 2; ++mq) {
        #pragma unroll
        for (int r = 0; r < 4; ++r) liacc[mq][r] = 0.f;
        #pragma unroll
        for (int dt = 0; dt < 4; ++dt)
            #pragma unroll
            for (int r = 0; r < 4; ++r) oacc[mq][dt][r] = 0.f;
    }

    int qcol[2] = { q0 + l15, q0 + 16 + l15 };
    int nkt = (qb32 >> 1) + 1;

    for (int kt = 0; kt < nkt; ++kt) {
        int k0 = kt * 64;
        __syncthreads();
        #pragma unroll
        for (int i = t; i < 512; i += 256) {
            int row = i >> 3, seg = i & 7;
            *reinterpret_cast<int4*>(&Ks[row][seg * 8]) =
                *reinterpret_cast<const int4*>(g_k + (size_t)(k0 + row) * KVW + hk * 64 + seg * 8);
            *reinterpret_cast<int4*>(&Vs[row][seg * 8]) =
                *reinterpret_cast<const int4*>(g_vT + (size_t)(hk * 64 + row) * S_LEN + k0 + seg * 8);
        }
        __syncthreads();

        bf16x8 ak[4][2];
        #pragma unroll
        for (int mk = 0; mk < 4; ++mk) {
            ak[mk][0] = *reinterpret_cast<const bf16x8*>(&Ks[mk * 16 + l15][quad * 8]);
            ak[mk][1] = *reinterpret_cast<const bf16x8*>(&Ks[mk * 16 + l15][32 + quad * 8]);
        }

        f32x4 sacc[4][2];
        #pragma unroll
        for (int mk = 0; mk < 4; ++mk)
            #pragma unroll
            for (int mq = 0; mq < 2; ++mq) {
                f32x4 s;
                #pragma unroll
                for (int r = 0; r < 4; ++r) s[r] = 0.f;
                s = __builtin_amdgcn_mfma_f32_16x16x32_bf16(ak[mk][0], aq[mq][0], s, 0, 0, 0);
                s = __builtin_amdgcn_mfma_f32_16x16x32_bf16(ak[mk][1], aq[mq][1], s, 0, 0, 0);
                sacc[mk][mq] = s;
            }

        s16x4 pas[4][2];
        #pragma unroll
        for (int mk = 0; mk < 4; ++mk)
            #pragma unroll
            for (int mq = 0; mq < 2; ++mq) {
                bf16x4 pa;
                #pragma unroll
                for (int r = 0; r < 4; ++r) {
                    int kk = k0 + mk * 16 + quad * 4 + r;
                    pa[r] = (bf16_t)((kk <= qcol[mq]) ? __expf(sacc[mk][mq][r] - 16.0f) : 0.0f);
                }
                pas[mk][mq] = bc4(pa);
            }

        #pragma unroll
        for (int mk = 0; mk < 4; ++mk) {
            #pragma unroll
            for (int dt = 0; dt < 4; ++dt) {
                bf16x4 bv = *reinterpret_cast<const bf16x4*>(&Vs[dt * 16 + l15][mk * 16 + quad * 4]);
                s16x4 bvs = bc4(bv);
                #pragma unroll
                for (int mq = 0; mq < 2; ++mq)
                    oacc[mq][dt] = __builtin_amdgcn_mfma_f32_16x16x16bf16_1k(pas[mk][mq], bvs, oacc[mq][dt], 0, 0, 0);
            }
            #pragma unroll
            for (int mq = 0; mq < 2; ++mq)
                liacc[mq] = __builtin_amdgcn_mfma_f32_16x16x16bf16_1k(pas[mk][mq], ones_s, liacc[mq], 0, 0, 0);
        }
    }

    #pragma unroll
    for (int mq = 0; mq < 2; ++mq)
        #pragma unroll
        for (int r = 0; r < 4; ++r) {
            float inv = 1.0f / liacc[mq][r];
            int row = q0 + mq * 16 + quad * 4 + r;
            #pragma unroll
            for (int dt = 0; dt < 4; ++dt)
                g_om[(size_t)row * HID + head * 64 + dt * 16 + l15] = (bf16_t)(oacc[mq][dt][r] * inv);
        }
}

// ---------------------------------------------------------------------------
// Launch: 4 dispatches.
// ---------------------------------------------------------------------------
extern "C" void kernel_launch(void* const* d_in, const int* in_sizes, int n_in,
                              void* d_out, int out_size, void* d_ws, size_t ws_size,
                              hipStream_t stream) {
    const float* x    = (const float*)d_in[0];
    const float* qpW  = (const float*)d_in[1];
    const float* kpW  = (const float*)d_in[2];
    const float* vpW  = (const float*)d_in[3];
    const float* opW  = (const float*)d_in[4];
    const void*  invf = d_in[5];
    float* out = (float*)d_out;

    prep_kernel<<<6912, 256, 0, stream>>>(x, qpW, kpW, vpW, opW, invf);
    gemm_fused_kernel<<<dim3(24, 32), 256, 0, stream>>>(nullptr, 0);   // QKV
    flash_kernel<<<512, 256, 0, stream>>>();
    gemm_fused_kernel<<<dim3(16, 32), 256, 0, stream>>>(out, 1);       // O
}

// Round 11
// 251.618 us; speedup vs baseline: 2.2293x; 1.0263x over previous
//
#include <hip/hip_runtime.h>

// ---------------------------------------------------------------------------
// SelfAttention (GQA + nonstandard RoPE), S=2048, HIDDEN=2048, 32 q-heads,
// 8 kv-heads, D=64.  Inputs/outputs FLOAT32; internal bf16 MFMA, fp32 accum.
// R11: flash split by KEY CHUNKS (fixed-shift softmax is linear: partial O
// and l over disjoint key ranges ADD).  flash_part: <=8 64-key tiles per
// block (balanced, ~1280 live blocks); flash_combine: sum partials, divide,
// cast.  GEMMs (BK=64 dbuf global_load_lds) & prep unchanged from R9b.
// ---------------------------------------------------------------------------

typedef __bf16 bf16_t;
typedef __bf16 bf16x4 __attribute__((ext_vector_type(4)));
typedef __bf16 bf16x8 __attribute__((ext_vector_type(8)));
typedef float  f32x4  __attribute__((ext_vector_type(4)));
typedef short  s16x4  __attribute__((ext_vector_type(4)));

#define S_LEN   2048
#define HID     2048
#define NKV     8
#define NH      32
#define DHEAD   64
#define KVW     (NKV * DHEAD)   // 512

// ---- module-global scratch (rewritten fully each call) ---------------------
__device__ __align__(16) bf16_t g_xb [S_LEN * HID];     // x in bf16
__device__ __align__(16) bf16_t g_wTq[HID * HID];       // q_proj^T  [N][K]
__device__ __align__(16) bf16_t g_wTk[KVW * HID];       // k_proj^T
__device__ __align__(16) bf16_t g_wTv[KVW * HID];       // v_proj^T
__device__ __align__(16) bf16_t g_wTo[HID * HID];       // o_proj^T
__device__ __align__(16) bf16_t g_q [S_LEN * HID];      // roped Q
__device__ __align__(16) bf16_t g_k [S_LEN * KVW];      // roped K
__device__ __align__(16) bf16_t g_vT[KVW * S_LEN];      // V^T [d_total][S]
__device__ __align__(16) bf16_t g_om[S_LEN * HID];      // attn out (pre o_proj)
__device__ float g_ropeC[S_LEN * 32];
__device__ float g_ropeS[S_LEN * 32];
__device__ __align__(16) float g_po[4u * S_LEN * HID];  // partial O, per key-chunk
__device__ float g_pl[4u * S_LEN * NH];                 // partial l

static __device__ inline s16x4 bc4(bf16x4 v) { s16x4 r; __builtin_memcpy(&r, &v, 8); return r; }

// async 16B global -> LDS.  lds base wave-uniform; data lands at base+lane*16.
__device__ __forceinline__ void gll16(void* lds, const void* g) {
    __builtin_amdgcn_global_load_lds(
        (const __attribute__((address_space(1))) void*)g,
        (__attribute__((address_space(3))) void*)lds,
        16, 0, 0);
}

// ---------------------------------------------------------------------------
// prep: (a) RoPE table (f64-exact; inv_freq dtype sniff), (b) x f32->bf16,
// (c) four weight transposes f32 [R][C] -> bf16 [C][R].
// ---------------------------------------------------------------------------
__global__ __launch_bounds__(256)
void prep_kernel(const float* __restrict__ x,
                 const float* __restrict__ qw, const float* __restrict__ kw,
                 const float* __restrict__ vw, const float* __restrict__ ow,
                 const void* __restrict__ invf_raw) {
    __shared__ bf16_t tile[64][65];
    int b = blockIdx.x, t = threadIdx.x;

    if (b < 256) {                               // RoPE table: 65536 entries
        int idx = b * 256 + t;
        int s = idx >> 5, j = idx & 31;
        float f;
        if (*(const unsigned*)invf_raw == 0x3F800000u) {
            f = ((const float*)invf_raw)[j];
        } else {
            unsigned u = ((unsigned)((const unsigned short*)invf_raw)[j]) << 16;
            __builtin_memcpy(&f, &u, 4);
        }
        double a = (double)s * (double)f;
        g_ropeC[idx] = (float)cos(a);
        g_ropeS[idx] = (float)sin(a);
        return;
    }
    if (b < 4352) {                              // x convert: 1M float4
        int idx = (b - 256) * 256 + t;
        float4 v = reinterpret_cast<const float4*>(x)[idx];
        bf16x4 o;
        o[0] = (bf16_t)v.x; o[1] = (bf16_t)v.y; o[2] = (bf16_t)v.z; o[3] = (bf16_t)v.w;
        *reinterpret_cast<bf16x4*>(&g_xb[(size_t)idx * 4]) = o;
        return;
    }
    const float* in; bf16_t* outp; int R, C, tb;
    if (b < 5376)      { in = qw; outp = g_wTq; R = HID; C = HID; tb = b - 4352; }
    else if (b < 5632) { in = kw; outp = g_wTk; R = HID; C = KVW; tb = b - 5376; }
    else if (b < 5888) { in = vw; outp = g_wTv; R = HID; C = KVW; tb = b - 5632; }
    else               { in = ow; outp = g_wTo; R = HID; C = HID; tb = b - 5888; }
    int xt = C >> 6;
    int c0 = (tb % xt) * 64, r0 = (tb / xt) * 64;
    int tx = t & 63, ty = t >> 6;
    #pragma unroll
    for (int r = ty; r < 64; r += 4)
        tile[r][tx] = (bf16_t)in[(size_t)(r0 + r) * C + c0 + tx];
    __syncthreads();
    #pragma unroll
    for (int r = ty; r < 64; r += 4)
        outp[(size_t)(c0 + r) * R + r0 + tx] = tile[tx][r];
}

// ---------------------------------------------------------------------------
// Fused MFMA GEMM, 64x128 block tile, BK=64, double-buffered LDS (R9b).
// which=0: QKV fused over bx (0-15 Q+RoPE, 16-19 K+RoPE, 20-23 V transp).
// which=1: O, f32 out.
// ---------------------------------------------------------------------------
__global__ __launch_bounds__(256)
void gemm_fused_kernel(float* __restrict__ Cf, int which) {
    __shared__ __align__(16) bf16_t As[2][64 * 64];     // 8 chunks / buf
    __shared__ __align__(16) bf16_t Bs[2][128 * 64];    // 16 chunks / buf

    int t    = threadIdx.x;
    int lane = t & 63, wid = t >> 6;
    int quad = lane >> 4, l15 = lane & 15;
    int bx = blockIdx.x, m0 = blockIdx.y * 64;
    int wm = (wid >> 1) * 32, wn = (wid & 1) * 64;

    const bf16_t* A; const bf16_t* Bt; int n0;
    if (which == 1)      { A = g_om; Bt = g_wTo; n0 = bx * 128; }
    else {
        A = g_xb;
        if (bx < 16)      { Bt = g_wTq; n0 = bx * 128; }
        else if (bx < 20) { Bt = g_wTk; n0 = (bx - 16) * 128; }
        else              { Bt = g_wTv; n0 = (bx - 20) * 128; }
    }

    int crow = lane >> 3;                        // row within 8-row chunk
    int gseg = (lane & 7) ^ crow;                // swizzled 16B source octet
    int so   = l15 & 7;                          // read-side row swizzle key

    f32x4 acc[2][4];
    #pragma unroll
    for (int im = 0; im < 2; ++im)
        #pragma unroll
        for (int in = 0; in < 4; ++in)
            #pragma unroll
            for (int r = 0; r < 4; ++r) acc[im][in][r] = 0.f;

    auto stage = [&](int buf, int kt) {
        int ca0 = wid * 2, cb0 = wid * 4;
        gll16(&As[buf][(ca0 + 0) * 512], A  + (size_t)(m0 + (ca0 + 0) * 8 + crow) * HID + kt + gseg * 8);
        gll16(&As[buf][(ca0 + 1) * 512], A  + (size_t)(m0 + (ca0 + 1) * 8 + crow) * HID + kt + gseg * 8);
        gll16(&Bs[buf][(cb0 + 0) * 512], Bt + (size_t)(n0 + (cb0 + 0) * 8 + crow) * HID + kt + gseg * 8);
        gll16(&Bs[buf][(cb0 + 1) * 512], Bt + (size_t)(n0 + (cb0 + 1) * 8 + crow) * HID + kt + gseg * 8);
        gll16(&Bs[buf][(cb0 + 2) * 512], Bt + (size_t)(n0 + (cb0 + 2) * 8 + crow) * HID + kt + gseg * 8);
        gll16(&Bs[buf][(cb0 + 3) * 512], Bt + (size_t)(n0 + (cb0 + 3) * 8 + crow) * HID + kt + gseg * 8);
    };

    stage(0, 0);                                  // preload buf 0

    for (int it = 0; it < 32; ++it) {
        int cur = it & 1;
        __syncthreads();                          // buf[cur] ready; buf[1-cur] free
        if (it + 1 < 32)
            stage(cur ^ 1, (it + 1) * 64);        // in flight during compute

        bf16x8 af[2][2], bfr[4][2];
        #pragma unroll
        for (int im = 0; im < 2; ++im)
            #pragma unroll
            for (int kh = 0; kh < 2; ++kh)
                af[im][kh] = *reinterpret_cast<const bf16x8*>(
                    &As[cur][(wm + im * 16 + l15) * 64 + (((kh * 4 + quad) ^ so) * 8)]);
        #pragma unroll
        for (int in = 0; in < 4; ++in)
            #pragma unroll
            for (int kh = 0; kh < 2; ++kh)
                bfr[in][kh] = *reinterpret_cast<const bf16x8*>(
                    &Bs[cur][(wn + in * 16 + l15) * 64 + (((kh * 4 + quad) ^ so) * 8)]);
        #pragma unroll
        for (int im = 0; im < 2; ++im)
            #pragma unroll
            for (int in = 0; in < 4; ++in)
                #pragma unroll
                for (int kh = 0; kh < 2; ++kh)
                    acc[im][in] = __builtin_amdgcn_mfma_f32_16x16x32_bf16(
                        af[im][kh], bfr[in][kh], acc[im][in], 0, 0, 0);
    }

    if (which == 1) {                            // O: f32 row-major
        #pragma unroll
        for (int im = 0; im < 2; ++im) {
            int rowb = m0 + wm + im * 16 + quad * 4;
            #pragma unroll
            for (int in = 0; in < 4; ++in) {
                int col = bx * 128 + wn + in * 16 + l15;
                #pragma unroll
                for (int r = 0; r < 4; ++r)
                    Cf[(size_t)(rowb + r) * HID + col] = acc[im][in][r];
            }
        }
    } else if (bx < 20) {                        // Q/K: RoPE epilogue -> bf16
        bf16_t* Cb; int N, colbase;
        if (bx < 16) { Cb = g_q; N = HID; colbase = bx * 128 + wn; }
        else         { Cb = g_k; N = KVW; colbase = (bx - 16) * 128 + wn; }
        // out[d] = x[d]*cos + x[d+32]*sin ; out[d+32] = x[d]*sin - x[d+32]*cos
        #pragma unroll
        for (int im = 0; im < 2; ++im) {
            #pragma unroll
            for (int r = 0; r < 4; ++r) {
                int row = m0 + wm + im * 16 + quad * 4 + r;
                #pragma unroll
                for (int in = 0; in < 2; ++in) {
                    int d = in * 16 + l15;                 // 0..31
                    float a  = acc[im][in][r];
                    float bb = acc[im][in + 2][r];
                    float cc = g_ropeC[row * 32 + d];
                    float ss = g_ropeS[row * 32 + d];
                    Cb[(size_t)row * N + colbase + d]      = (bf16_t)(a * cc + bb * ss);
                    Cb[(size_t)row * N + colbase + 32 + d] = (bf16_t)(a * ss - bb * cc);
                }
            }
        }
    } else {                                     // V: transposed store -> g_vT
        #pragma unroll
        for (int im = 0; im < 2; ++im) {
            int rowb = m0 + wm + im * 16 + quad * 4;
            #pragma unroll
            for (int in = 0; in < 4; ++in) {
                int col = (bx - 20) * 128 + wn + in * 16 + l15;
                #pragma unroll
                for (int r = 0; r < 4; ++r)
                    g_vT[(size_t)col * S_LEN + (rowb + r)] = (bf16_t)acc[im][in][r];
            }
        }
    }
}

// ---------------------------------------------------------------------------
// Flash attention, key-chunked partials (causal, GQA, register-only P).
// Block = 4 waves = 4 q-heads of kv-group hk; 32 queries/wave.  Block
// (hk, qb32, chunk) processes key tiles [8*chunk, min(8*chunk+8, nkt));
// blocks past the causal range exit.  Fixed-shift softmax p=exp(s-16) is
// linear over key chunks, so raw f32 (O, l) partials add in the combine.
// ---------------------------------------------------------------------------
__global__ __launch_bounds__(256)
void flash_part_kernel() {
    __shared__ __align__(16) bf16_t Ks[64][72];   // [key][d]
    __shared__ __align__(16) bf16_t Vs[64][72];   // [d][key]

    int t    = threadIdx.x;
    int lane = t & 63, wid = t >> 6;
    int quad = lane >> 4, l15 = lane & 15;
    int bx   = blockIdx.x;
    int hk   = bx & 7;
    int qb32 = (bx >> 3) & 63;
    int chunk = bx >> 9;                  // 0..3
    int nkt  = (qb32 >> 1) + 1;           // 64-key tiles covering k <= q0+31
    int kt0  = chunk * 8;
    if (kt0 >= nkt) return;               // empty chunk (before any barrier)
    int kt1  = min(kt0 + 8, nkt);

    int head = hk * 4 + wid;
    int q0   = qb32 * 32;

    bf16x8 aq[2][2];
    #pragma unroll
    for (int mq = 0; mq < 2; ++mq) {
        const bf16_t* qp = g_q + (size_t)(q0 + mq * 16 + l15) * HID + head * 64 + quad * 8;
        aq[mq][0] = *reinterpret_cast<const bf16x8*>(qp);
        aq[mq][1] = *reinterpret_cast<const bf16x8*>(qp + 32);
        #pragma unroll
        for (int j = 0; j < 8; ++j) {
            aq[mq][0][j] = (bf16_t)((float)aq[mq][0][j] * 0.125f);  // exact
            aq[mq][1][j] = (bf16_t)((float)aq[mq][1][j] * 0.125f);
        }
    }

    bf16x4 ones4;
    #pragma unroll
    for (int j = 0; j < 4; ++j) ones4[j] = (bf16_t)1.0f;
    s16x4 ones_s = bc4(ones4);

    f32x4 oacc[2][4], liacc[2];
    #pragma unroll
    for (int mq = 0; mq < 2; ++mq) {
        #pragma unroll
        for (int r = 0; r < 4; ++r) liacc[mq][r] = 0.f;
        #pragma unroll
        for (int dt = 0; dt < 4; ++dt)
            #pragma unroll
            for (int r = 0; r < 4; ++r) oacc[mq][dt][r] = 0.f;
    }

    int qcol[2] = { q0 + l15, q0 + 16 + l15 };

    for (int kt = kt0; kt < kt1; ++kt) {
        int k0 = kt * 64;
        __syncthreads();
        #pragma unroll
        for (int i = t; i < 512; i += 256) {
            int row = i >> 3, seg = i & 7;
            *reinterpret_cast<int4*>(&Ks[row][seg * 8]) =
                *reinterpret_cast<const int4*>(g_k + (size_t)(k0 + row) * KVW + hk * 64 + seg * 8);
            *reinterpret_cast<int4*>(&Vs[row][seg * 8]) =
                *reinterpret_cast<const int4*>(g_vT + (size_t)(hk * 64 + row) * S_LEN + k0 + seg * 8);
        }
        __syncthreads();

        bf16x8 ak[4][2];
        #pragma unroll
        for (int mk = 0; mk < 4; ++mk) {
            ak[mk][0] = *reinterpret_cast<const bf16x8*>(&Ks[mk * 16 + l15][quad * 8]);
            ak[mk][1] = *reinterpret_cast<const bf16x8*>(&Ks[mk * 16 + l15][32 + quad * 8]);
        }

        f32x4 sacc[4][2];
        #pragma unroll
        for (int mk = 0; mk < 4; ++mk)
            #pragma unroll
            for (int mq = 0; mq < 2; ++mq) {
                f32x4 s;
                #pragma unroll
                for (int r = 0; r < 4; ++r) s[r] = 0.f;
                s = __builtin_amdgcn_mfma_f32_16x16x32_bf16(ak[mk][0], aq[mq][0], s, 0, 0, 0);
                s = __builtin_amdgcn_mfma_f32_16x16x32_bf16(ak[mk][1], aq[mq][1], s, 0, 0, 0);
                sacc[mk][mq] = s;
            }

        s16x4 pas[4][2];
        #pragma unroll
        for (int mk = 0; mk < 4; ++mk)
            #pragma unroll
            for (int mq = 0; mq < 2; ++mq) {
                bf16x4 pa;
                #pragma unroll
                for (int r = 0; r < 4; ++r) {
                    int kk = k0 + mk * 16 + quad * 4 + r;
                    pa[r] = (bf16_t)((kk <= qcol[mq]) ? __expf(sacc[mk][mq][r] - 16.0f) : 0.0f);
                }
                pas[mk][mq] = bc4(pa);
            }

        #pragma unroll
        for (int mk = 0; mk < 4; ++mk) {
            #pragma unroll
            for (int dt = 0; dt < 4; ++dt) {
                bf16x4 bv = *reinterpret_cast<const bf16x4*>(&Vs[dt * 16 + l15][mk * 16 + quad * 4]);
                s16x4 bvs = bc4(bv);
                #pragma unroll
                for (int mq = 0; mq < 2; ++mq)
                    oacc[mq][dt] = __builtin_amdgcn_mfma_f32_16x16x16bf16_1k(pas[mk][mq], bvs, oacc[mq][dt], 0, 0, 0);
            }
            #pragma unroll
            for (int mq = 0; mq < 2; ++mq)
                liacc[mq] = __builtin_amdgcn_mfma_f32_16x16x16bf16_1k(pas[mk][mq], ones_s, liacc[mq], 0, 0, 0);
        }
    }

    // store raw partials (f32): O row(q)=q0+mq*16+quad*4+r, col(d)=dt*16+l15.
    float* po = g_po + (size_t)chunk * S_LEN * HID;
    #pragma unroll
    for (int mq = 0; mq < 2; ++mq)
        #pragma unroll
        for (int r = 0; r < 4; ++r) {
            int row = q0 + mq * 16 + quad * 4 + r;
            #pragma unroll
            for (int dt = 0; dt < 4; ++dt)
                po[(size_t)row * HID + head * 64 + dt * 16 + l15] = oacc[mq][dt][r];
            if (l15 == 0)
                g_pl[((size_t)chunk * S_LEN + row) * NH + head] = liacc[mq][r];
        }
}

// ---------------------------------------------------------------------------
// Combine partials: g_om[q][hd] = (sum_c O_c) / (sum_c l_c), cast bf16.
// One thread = 4 contiguous d of one (q, head).  nc derived from q.
// ---------------------------------------------------------------------------
__global__ __launch_bounds__(256)
void flash_combine_kernel() {
    int t = blockIdx.x * 256 + threadIdx.x;      // 0 .. 1M-1
    int row  = t >> 9;                           // q
    int col4 = (t & 511) * 4;                    // d-group
    int head = col4 >> 6;
    int nkt  = ((row >> 5) >> 1) + 1;
    int nc   = (nkt + 7) >> 3;                   // 1..4 chunks

    float4 s = make_float4(0.f, 0.f, 0.f, 0.f);
    float l = 0.f;
    for (int c = 0; c < nc; ++c) {
        const float4 v = *reinterpret_cast<const float4*>(
            g_po + ((size_t)c * S_LEN + row) * HID + col4);
        s.x += v.x; s.y += v.y; s.z += v.z; s.w += v.w;
        l += g_pl[((size_t)c * S_LEN + row) * NH + head];
    }
    float inv = 1.0f / l;
    bf16x4 o;
    o[0] = (bf16_t)(s.x * inv); o[1] = (bf16_t)(s.y * inv);
    o[2] = (bf16_t)(s.z * inv); o[3] = (bf16_t)(s.w * inv);
    *reinterpret_cast<bf16x4*>(&g_om[(size_t)row * HID + col4]) = o;
}

// ---------------------------------------------------------------------------
// Launch: 5 dispatches.
// ---------------------------------------------------------------------------
extern "C" void kernel_launch(void* const* d_in, const int* in_sizes, int n_in,
                              void* d_out, int out_size, void* d_ws, size_t ws_size,
                              hipStream_t stream) {
    const float* x    = (const float*)d_in[0];
    const float* qpW  = (const float*)d_in[1];
    const float* kpW  = (const float*)d_in[2];
    const float* vpW  = (const float*)d_in[3];
    const float* opW  = (const float*)d_in[4];
    const void*  invf = d_in[5];
    float* out = (float*)d_out;

    prep_kernel<<<6912, 256, 0, stream>>>(x, qpW, kpW, vpW, opW, invf);
    gemm_fused_kernel<<<dim3(24, 32), 256, 0, stream>>>(nullptr, 0);   // QKV
    flash_part_kernel<<<2048, 256, 0, stream>>>();                     // 8kv x 64qb x 4chunk
    flash_combine_kernel<<<4096, 256, 0, stream>>>();
    gemm_fused_kernel<<<dim3(16, 32), 256, 0, stream>>>(out, 1);       // O
}